// Round 1
// baseline (280.524 us; speedup 1.0000x reference)
//
#include <hip/hip_runtime.h>
#include <math.h>

#define B 8
#define N 4096
#define D 256
#define BN (B*N)
#define L 16
#define NC (N/L)      // 256 chunks per batch
#define NC1 (NC+1)    // 257 (exclusive prefix + total)

// ---------------- K1: f1 = seq@w1 + b1, f2 = seq@w2 + b2 (one wave per row) ----
__global__ __launch_bounds__(256) void k_f1f2(const float* __restrict__ seq,
    const float* __restrict__ w1, const float* __restrict__ b1,
    const float* __restrict__ w2, const float* __restrict__ b2,
    float* __restrict__ f1, float* __restrict__ f2) {
  int wave = threadIdx.x >> 6;
  int lane = threadIdx.x & 63;
  long row = (long)blockIdx.x * 4 + wave;          // 0..BN-1
  float4 v = ((const float4*)(seq + row * D))[lane];
  float4 a = ((const float4*)w1)[lane];
  float4 b = ((const float4*)w2)[lane];
  float s1 = v.x*a.x + v.y*a.y + v.z*a.z + v.w*a.w;
  float s2 = v.x*b.x + v.y*b.y + v.z*b.z + v.w*b.w;
  for (int off = 32; off; off >>= 1) {
    s1 += __shfl_xor(s1, off, 64);
    s2 += __shfl_xor(s2, off, 64);
  }
  if (lane == 0) { f1[row] = s1 + b1[0]; f2[row] = s2 + b2[0]; }
}

// ---------------- K2: rank f2 per batch (counting sort, stable) ----------------
__global__ __launch_bounds__(256) void k_rank(const float* __restrict__ f2,
    float* __restrict__ sF2, int* __restrict__ sIdx,
    float* __restrict__ e2lo, float* __restrict__ e2hi) {
  __shared__ float lf[N];
  int b = blockIdx.y;
  const float* fb = f2 + (long)b * N;
  for (int t = threadIdx.x; t < N; t += 256) lf[t] = fb[t];
  __syncthreads();
  int j = blockIdx.x * 256 + threadIdx.x;
  float v = lf[j];
  int cnt = 0;
  #pragma unroll 8
  for (int p = 0; p < N; ++p) {
    float x = lf[p];
    cnt += (x < v) || (x == v && p < j);
  }
  long o = (long)b * N + cnt;
  sF2[o] = v;
  sIdx[o] = j;
  e2lo[o] = expf(0.01f * v);
  e2hi[o] = expf(v);
}

// ---------------- K3: Vs[pos] = seq[idx[pos]] @ W  (fp32 64x64 tile) ----------
__global__ __launch_bounds__(256) void k_gemm(const float* __restrict__ seq,
    const float* __restrict__ W, const int* __restrict__ sIdx,
    float* __restrict__ Vs) {
  __shared__ float As[16][68];   // [k][m]
  __shared__ float Bs[16][68];   // [k][n]
  int b = blockIdx.z;
  int mBase = blockIdx.x * 64;
  int nBase = blockIdx.y * 64;
  int tid = threadIdx.x;
  int ty = tid >> 4, tx = tid & 15;
  int ar = tid >> 2;          // row in tile 0..63
  int aq = tid & 3;           // which float4 of the 16-wide k strip
  long aRow = sIdx[(long)b * N + mBase + ar];
  const float* aPtr = seq + (((long)b * N + aRow) * D);
  int br = tid >> 4;          // k row 0..15
  int bc4 = (tid & 15) * 4;   // col 0..60
  float acc[4][4];
  #pragma unroll
  for (int i = 0; i < 4; ++i)
    #pragma unroll
    for (int j = 0; j < 4; ++j) acc[i][j] = 0.f;

  for (int kt = 0; kt < D; kt += 16) {
    float4 av = *(const float4*)(aPtr + kt + aq * 4);
    float4 bv = *(const float4*)(W + (long)(kt + br) * D + nBase + bc4);
    __syncthreads();
    As[aq*4+0][ar] = av.x; As[aq*4+1][ar] = av.y;
    As[aq*4+2][ar] = av.z; As[aq*4+3][ar] = av.w;
    *(float4*)&Bs[br][bc4] = bv;
    __syncthreads();
    #pragma unroll
    for (int k = 0; k < 16; ++k) {
      float4 aa = *(const float4*)&As[k][ty*4];
      float4 bb = *(const float4*)&Bs[k][tx*4];
      acc[0][0] += aa.x*bb.x; acc[0][1] += aa.x*bb.y; acc[0][2] += aa.x*bb.z; acc[0][3] += aa.x*bb.w;
      acc[1][0] += aa.y*bb.x; acc[1][1] += aa.y*bb.y; acc[1][2] += aa.y*bb.z; acc[1][3] += aa.y*bb.w;
      acc[2][0] += aa.z*bb.x; acc[2][1] += aa.z*bb.y; acc[2][2] += aa.z*bb.z; acc[2][3] += aa.z*bb.w;
      acc[3][0] += aa.w*bb.x; acc[3][1] += aa.w*bb.y; acc[3][2] += aa.w*bb.z; acc[3][3] += aa.w*bb.w;
    }
  }
  #pragma unroll
  for (int mm = 0; mm < 4; ++mm) {
    float4 o = make_float4(acc[mm][0], acc[mm][1], acc[mm][2], acc[mm][3]);
    *(float4*)(Vs + ((long)b * N + mBase + ty*4 + mm) * D + nBase + tx*4) = o;
  }
}

// ---------------- K4a: per-chunk weighted sums ---------------------------------
__global__ __launch_bounds__(256) void k_chunks(const float* __restrict__ Vs,
    const float* __restrict__ e2lo, const float* __restrict__ e2hi,
    float* __restrict__ PrefLo, float* __restrict__ PrefHi,
    float* __restrict__ ScalLo, float* __restrict__ ScalHi) {
  int c = blockIdx.x, b = blockIdx.y, d = threadIdx.x;
  long base = (long)b * N + c * L;
  float alo = 0.f, ahi = 0.f, slo = 0.f, shi = 0.f;
  #pragma unroll 4
  for (int r = 0; r < L; ++r) {
    float wlo = e2lo[base + r], whi = e2hi[base + r];
    float v = Vs[(base + r) * D + d];
    alo += wlo * v; ahi += whi * v;
    slo += wlo;     shi += whi;
  }
  PrefLo[((long)b * NC1 + c) * D + d] = alo;
  PrefHi[((long)b * NC1 + c) * D + d] = ahi;
  if (d == 0) { ScalLo[b * NC1 + c] = slo; ScalHi[b * NC1 + c] = shi; }
}

// ---------------- K4b: in-place exclusive scan over chunks ---------------------
__global__ __launch_bounds__(256) void k_scan(float* __restrict__ PrefLo,
    float* __restrict__ PrefHi, float* __restrict__ ScalLo, float* __restrict__ ScalHi) {
  int b = blockIdx.x, d = threadIdx.x;
  long base = (long)b * NC1 * D + d;
  float runLo = 0.f, runHi = 0.f;
  for (int c = 0; c < NC; ++c) {
    long o = base + (long)c * D;
    float tl = PrefLo[o], th = PrefHi[o];
    PrefLo[o] = runLo; PrefHi[o] = runHi;
    runLo += tl; runHi += th;
  }
  PrefLo[base + (long)NC * D] = runLo;
  PrefHi[base + (long)NC * D] = runHi;
  if (d == 0) {
    float r = 0.f;
    for (int c = 0; c < NC; ++c) { float t = ScalLo[b*NC1+c]; ScalLo[b*NC1+c] = r; r += t; }
    ScalLo[b*NC1+NC] = r;
  }
  if (d == 1) {
    float r = 0.f;
    for (int c = 0; c < NC; ++c) { float t = ScalHi[b*NC1+c]; ScalHi[b*NC1+c] = r; r += t; }
    ScalHi[b*NC1+NC] = r;
  }
}

// ---------------- K5: combine + normalize + bias + relu ------------------------
__global__ __launch_bounds__(256) void k_combine(const float* __restrict__ f1,
    const float* __restrict__ sF2, const float* __restrict__ e2lo,
    const float* __restrict__ e2hi, const float* __restrict__ Vs,
    const float* __restrict__ PrefLo, const float* __restrict__ PrefHi,
    const float* __restrict__ ScalLo, const float* __restrict__ ScalHi,
    const float* __restrict__ bias, float* __restrict__ out) {
  int b = blockIdx.y, d = threadIdx.x;
  float bs = bias[0];
  for (int rr = 0; rr < 4; ++rr) {
    int i = blockIdx.x * 4 + rr;
    float f1v = f1[(long)b * N + i];
    float a  = expf(f1v);
    float cc = expf(0.01f * f1v);
    float t = -f1v;
    const float* sb = sF2 + (long)b * N;
    int lo = 0, hi = N;
    while (lo < hi) { int mid = (lo + hi) >> 1; if (sb[mid] <= t) lo = mid + 1; else hi = mid; }
    int k = lo;                     // #(f2_j <= -f1_i): Lo set = ranks [0,k)
    int c0 = k >> 4;                // chunk index (L=16)
    float resLo = 0.f, resHi = 0.f, szLo = 0.f, szHi = 0.f;
    for (int r = c0 * L; r < k; ++r) {
      float wlo = e2lo[(long)b*N + r], whi = e2hi[(long)b*N + r];
      float v = Vs[((long)b*N + r) * D + d];
      resLo += wlo * v; resHi += whi * v;
      szLo  += wlo;     szHi  += whi;
    }
    long pb = ((long)b * NC1 + c0) * D + d;
    long pt = ((long)b * NC1 + NC) * D + d;
    float Slo = PrefLo[pb] + resLo;
    float Shi = PrefHi[pt] - PrefHi[pb] - resHi;
    float Zlo = ScalLo[b*NC1 + c0] + szLo;
    float Zhi = ScalHi[b*NC1 + NC] - ScalHi[b*NC1 + c0] - szHi;
    float Z = a * Zhi + cc * Zlo;
    float o = (a * Shi + cc * Slo) / Z + bs;
    out[((long)b * N + i) * D + d] = fmaxf(o, 0.f);
  }
}

// ---------------- launch -------------------------------------------------------
extern "C" void kernel_launch(void* const* d_in, const int* in_sizes, int n_in,
                              void* d_out, int out_size, void* d_ws, size_t ws_size,
                              hipStream_t stream) {
  const float* seq  = (const float*)d_in[0];
  const float* Wf   = (const float*)d_in[1];
  const float* w1   = (const float*)d_in[2];
  const float* b1   = (const float*)d_in[3];
  const float* w2   = (const float*)d_in[4];
  const float* b2   = (const float*)d_in[5];
  const float* bias = (const float*)d_in[6];
  float* out = (float*)d_out;

  // workspace layout (floats)
  size_t need = (size_t)(5*BN + BN /*int*/ + (size_t)BN*D + 2*(size_t)B*NC1*D + 2*(size_t)B*NC1) * 4;
  if (ws_size < need) return;  // fail loudly (wrong output) rather than corrupt
  float* f1    = (float*)d_ws;
  float* f2    = f1 + BN;
  float* sF2   = f2 + BN;
  float* e2lo  = sF2 + BN;
  float* e2hi  = e2lo + BN;
  int*   sIdx  = (int*)(e2hi + BN);
  float* Vs    = (float*)(sIdx + BN);
  float* PrefLo = Vs + (size_t)BN * D;
  float* PrefHi = PrefLo + (size_t)B * NC1 * D;
  float* ScalLo = PrefHi + (size_t)B * NC1 * D;
  float* ScalHi = ScalLo + (size_t)B * NC1;

  k_f1f2<<<dim3(BN/4), 256, 0, stream>>>(seq, w1, b1, w2, b2, f1, f2);
  k_rank<<<dim3(N/256, B), 256, 0, stream>>>(f2, sF2, sIdx, e2lo, e2hi);
  k_gemm<<<dim3(N/64, D/64, B), 256, 0, stream>>>(seq, Wf, sIdx, Vs);
  k_chunks<<<dim3(NC, B), 256, 0, stream>>>(Vs, e2lo, e2hi, PrefLo, PrefHi, ScalLo, ScalHi);
  k_scan<<<dim3(B), 256, 0, stream>>>(PrefLo, PrefHi, ScalLo, ScalHi);
  k_combine<<<dim3(N/4, B), 256, 0, stream>>>(f1, sF2, e2lo, e2hi, Vs,
      PrefLo, PrefHi, ScalLo, ScalHi, bias, out);
}

// Round 2
// 195.778 us; speedup vs baseline: 1.4329x; 1.4329x over previous
//
#include <hip/hip_runtime.h>
#include <math.h>

#define B 8
#define N 4096
#define D 256
#define BN (B*N)
#define L 16
#define NC (N/L)      // 256 chunks per batch
#define NC1 (NC+1)    // 257 (exclusive prefix + total)

// ---------------- K1: f1 = seq@w1 + b1, f2 = seq@w2 + b2 (one wave per row) ----
__global__ __launch_bounds__(256) void k_f1f2(const float* __restrict__ seq,
    const float* __restrict__ w1, const float* __restrict__ b1,
    const float* __restrict__ w2, const float* __restrict__ b2,
    float* __restrict__ f1, float* __restrict__ f2) {
  int wave = threadIdx.x >> 6;
  int lane = threadIdx.x & 63;
  long row = (long)blockIdx.x * 4 + wave;          // 0..BN-1
  float4 v = ((const float4*)(seq + row * D))[lane];
  float4 a = ((const float4*)w1)[lane];
  float4 b = ((const float4*)w2)[lane];
  float s1 = v.x*a.x + v.y*a.y + v.z*a.z + v.w*a.w;
  float s2 = v.x*b.x + v.y*b.y + v.z*b.z + v.w*b.w;
  for (int off = 32; off; off >>= 1) {
    s1 += __shfl_xor(s1, off, 64);
    s2 += __shfl_xor(s2, off, 64);
  }
  if (lane == 0) { f1[row] = s1 + b1[0]; f2[row] = s2 + b2[0]; }
}

// ---------------- K2a: partial rank counts (tiled O(N^2), 64-bit keys) ---------
// key = (monotone(f2 bits) << 12) | j  -> strict < gives stable rank directly.
__global__ __launch_bounds__(256) void k_rank_count(const float* __restrict__ f2,
    int* __restrict__ rank) {
  __shared__ unsigned long long skey[256];
  int b = blockIdx.z;
  int tid = threadIdx.x;
  const float* fb = f2 + (long)b * N;
  int p = blockIdx.y * 256 + tid;
  unsigned int up = __float_as_uint(fb[p]);
  up ^= (unsigned int)(((int)up >> 31) | 0x80000000);
  skey[tid] = ((unsigned long long)up << 12) | (unsigned)p;
  unsigned long long kj[4];
  int jbase = blockIdx.x * 1024;
  #pragma unroll
  for (int q = 0; q < 4; ++q) {
    int j = jbase + q * 256 + tid;
    unsigned int uj = __float_as_uint(fb[j]);
    uj ^= (unsigned int)(((int)uj >> 31) | 0x80000000);
    kj[q] = ((unsigned long long)uj << 12) | (unsigned)j;
  }
  __syncthreads();
  int c[4] = {0, 0, 0, 0};
  const ulonglong2* sk2 = (const ulonglong2*)skey;
  #pragma unroll 4
  for (int pp = 0; pp < 128; ++pp) {
    ulonglong2 kk = sk2[pp];
    #pragma unroll
    for (int q = 0; q < 4; ++q) {
      c[q] += (kk.x < kj[q]) ? 1 : 0;
      c[q] += (kk.y < kj[q]) ? 1 : 0;
    }
  }
  #pragma unroll
  for (int q = 0; q < 4; ++q)
    atomicAdd(&rank[(long)b * N + jbase + q * 256 + tid], c[q]);
}

// ---------------- K2b: scatter into sorted order -------------------------------
__global__ __launch_bounds__(256) void k_scatter(const float* __restrict__ f2,
    const int* __restrict__ rank, float* __restrict__ sF2, int* __restrict__ sIdx,
    float* __restrict__ e2lo, float* __restrict__ e2hi) {
  long idx = (long)blockIdx.x * 256 + threadIdx.x;   // 0..BN-1
  int b = (int)(idx >> 12);
  int j = (int)(idx & (N - 1));
  float v = f2[idx];
  int cnt = rank[idx];
  long o = (long)b * N + cnt;
  sF2[o] = v;
  sIdx[o] = j;
  e2lo[o] = expf(0.01f * v);
  e2hi[o] = expf(v);
}

// ---------------- K3: Vs[pos] = seq[idx[pos]] @ W  (fp32 64x64 tile) ----------
__global__ __launch_bounds__(256) void k_gemm(const float* __restrict__ seq,
    const float* __restrict__ W, const int* __restrict__ sIdx,
    float* __restrict__ Vs) {
  __shared__ float As[16][68];   // [k][m]
  __shared__ float Bs[16][68];   // [k][n]
  int b = blockIdx.z;
  int mBase = blockIdx.x * 64;
  int nBase = blockIdx.y * 64;
  int tid = threadIdx.x;
  int ty = tid >> 4, tx = tid & 15;
  int ar = tid >> 2;          // row in tile 0..63
  int aq = tid & 3;           // which float4 of the 16-wide k strip
  long aRow = sIdx[(long)b * N + mBase + ar];
  const float* aPtr = seq + (((long)b * N + aRow) * D);
  int br = tid >> 4;          // k row 0..15
  int bc4 = (tid & 15) * 4;   // col 0..60
  float acc[4][4];
  #pragma unroll
  for (int i = 0; i < 4; ++i)
    #pragma unroll
    for (int j = 0; j < 4; ++j) acc[i][j] = 0.f;

  for (int kt = 0; kt < D; kt += 16) {
    float4 av = *(const float4*)(aPtr + kt + aq * 4);
    float4 bv = *(const float4*)(W + (long)(kt + br) * D + nBase + bc4);
    __syncthreads();
    As[aq*4+0][ar] = av.x; As[aq*4+1][ar] = av.y;
    As[aq*4+2][ar] = av.z; As[aq*4+3][ar] = av.w;
    *(float4*)&Bs[br][bc4] = bv;
    __syncthreads();
    #pragma unroll
    for (int k = 0; k < 16; ++k) {
      float4 aa = *(const float4*)&As[k][ty*4];
      float4 bb = *(const float4*)&Bs[k][tx*4];
      acc[0][0] += aa.x*bb.x; acc[0][1] += aa.x*bb.y; acc[0][2] += aa.x*bb.z; acc[0][3] += aa.x*bb.w;
      acc[1][0] += aa.y*bb.x; acc[1][1] += aa.y*bb.y; acc[1][2] += aa.y*bb.z; acc[1][3] += aa.y*bb.w;
      acc[2][0] += aa.z*bb.x; acc[2][1] += aa.z*bb.y; acc[2][2] += aa.z*bb.z; acc[2][3] += aa.z*bb.w;
      acc[3][0] += aa.w*bb.x; acc[3][1] += aa.w*bb.y; acc[3][2] += aa.w*bb.z; acc[3][3] += aa.w*bb.w;
    }
  }
  #pragma unroll
  for (int mm = 0; mm < 4; ++mm) {
    float4 o = make_float4(acc[mm][0], acc[mm][1], acc[mm][2], acc[mm][3]);
    *(float4*)(Vs + ((long)b * N + mBase + ty*4 + mm) * D + nBase + tx*4) = o;
  }
}

// ---------------- K4a: per-chunk weighted sums ---------------------------------
__global__ __launch_bounds__(256) void k_chunks(const float* __restrict__ Vs,
    const float* __restrict__ e2lo, const float* __restrict__ e2hi,
    float* __restrict__ PrefLo, float* __restrict__ PrefHi,
    float* __restrict__ ScalLo, float* __restrict__ ScalHi) {
  int c = blockIdx.x, b = blockIdx.y, d = threadIdx.x;
  long base = (long)b * N + c * L;
  float alo = 0.f, ahi = 0.f, slo = 0.f, shi = 0.f;
  #pragma unroll 4
  for (int r = 0; r < L; ++r) {
    float wlo = e2lo[base + r], whi = e2hi[base + r];
    float v = Vs[(base + r) * D + d];
    alo += wlo * v; ahi += whi * v;
    slo += wlo;     shi += whi;
  }
  PrefLo[((long)b * NC1 + c) * D + d] = alo;
  PrefHi[((long)b * NC1 + c) * D + d] = ahi;
  if (d == 0) { ScalLo[b * NC1 + c] = slo; ScalHi[b * NC1 + c] = shi; }
}

// ---------------- K4b: exclusive scan over chunks (unroll-8, pipelined loads) --
__global__ __launch_bounds__(256) void k_scan(float* __restrict__ PrefLo,
    float* __restrict__ PrefHi, float* __restrict__ ScalLo, float* __restrict__ ScalHi) {
  int b = blockIdx.x, d = threadIdx.x;
  long base = (long)b * NC1 * D + d;
  float runLo = 0.f, runHi = 0.f;
  for (int cb = 0; cb < NC; cb += 8) {
    float tl[8], th[8];
    #pragma unroll
    for (int u = 0; u < 8; ++u) {
      long o = base + (long)(cb + u) * D;
      tl[u] = PrefLo[o]; th[u] = PrefHi[o];
    }
    #pragma unroll
    for (int u = 0; u < 8; ++u) {
      long o = base + (long)(cb + u) * D;
      PrefLo[o] = runLo; PrefHi[o] = runHi;
      runLo += tl[u]; runHi += th[u];
    }
  }
  PrefLo[base + (long)NC * D] = runLo;
  PrefHi[base + (long)NC * D] = runHi;
  if (d == 0) {
    float r = 0.f;
    for (int c = 0; c < NC; ++c) { float t = ScalLo[b*NC1+c]; ScalLo[b*NC1+c] = r; r += t; }
    ScalLo[b*NC1+NC] = r;
  }
  if (d == 1) {
    float r = 0.f;
    for (int c = 0; c < NC; ++c) { float t = ScalHi[b*NC1+c]; ScalHi[b*NC1+c] = r; r += t; }
    ScalHi[b*NC1+NC] = r;
  }
}

// ---------------- K5: combine + normalize + bias + relu ------------------------
__global__ __launch_bounds__(256) void k_combine(const float* __restrict__ f1,
    const float* __restrict__ sF2, const float* __restrict__ e2lo,
    const float* __restrict__ e2hi, const float* __restrict__ Vs,
    const float* __restrict__ PrefLo, const float* __restrict__ PrefHi,
    const float* __restrict__ ScalLo, const float* __restrict__ ScalHi,
    const float* __restrict__ bias, float* __restrict__ out) {
  int b = blockIdx.y, d = threadIdx.x;
  float bs = bias[0];
  for (int rr = 0; rr < 4; ++rr) {
    int i = blockIdx.x * 4 + rr;
    float f1v = f1[(long)b * N + i];
    float a  = expf(f1v);
    float cc = expf(0.01f * f1v);
    float t = -f1v;
    const float* sb = sF2 + (long)b * N;
    int lo = 0, hi = N;
    while (lo < hi) { int mid = (lo + hi) >> 1; if (sb[mid] <= t) lo = mid + 1; else hi = mid; }
    int k = lo;                     // #(f2_j <= -f1_i): Lo set = ranks [0,k)
    int c0 = k >> 4;                // chunk index (L=16)
    float resLo = 0.f, resHi = 0.f, szLo = 0.f, szHi = 0.f;
    for (int r = c0 * L; r < k; ++r) {
      float wlo = e2lo[(long)b*N + r], whi = e2hi[(long)b*N + r];
      float v = Vs[((long)b*N + r) * D + d];
      resLo += wlo * v; resHi += whi * v;
      szLo  += wlo;     szHi  += whi;
    }
    long pb = ((long)b * NC1 + c0) * D + d;
    long pt = ((long)b * NC1 + NC) * D + d;
    float Slo = PrefLo[pb] + resLo;
    float Shi = PrefHi[pt] - PrefHi[pb] - resHi;
    float Zlo = ScalLo[b*NC1 + c0] + szLo;
    float Zhi = ScalHi[b*NC1 + NC] - ScalHi[b*NC1 + c0] - szHi;
    float Z = a * Zhi + cc * Zlo;
    float o = (a * Shi + cc * Slo) / Z + bs;
    out[((long)b * N + i) * D + d] = fmaxf(o, 0.f);
  }
}

// ---------------- launch -------------------------------------------------------
extern "C" void kernel_launch(void* const* d_in, const int* in_sizes, int n_in,
                              void* d_out, int out_size, void* d_ws, size_t ws_size,
                              hipStream_t stream) {
  const float* seq  = (const float*)d_in[0];
  const float* Wf   = (const float*)d_in[1];
  const float* w1   = (const float*)d_in[2];
  const float* b1   = (const float*)d_in[3];
  const float* w2   = (const float*)d_in[4];
  const float* b2   = (const float*)d_in[5];
  const float* bias = (const float*)d_in[6];
  float* out = (float*)d_out;

  // workspace layout (floats)
  size_t need = (size_t)(7*BN + (size_t)BN*D + 2*(size_t)B*NC1*D + 2*(size_t)B*NC1) * 4;
  if (ws_size < need) return;  // fail loudly (wrong output) rather than corrupt
  float* f1    = (float*)d_ws;
  float* f2    = f1 + BN;
  float* sF2   = f2 + BN;
  float* e2lo  = sF2 + BN;
  float* e2hi  = e2lo + BN;
  int*   sIdx  = (int*)(e2hi + BN);
  int*   rank  = sIdx + BN;
  float* Vs    = (float*)(rank + BN);
  float* PrefLo = Vs + (size_t)BN * D;
  float* PrefHi = PrefLo + (size_t)B * NC1 * D;
  float* ScalLo = PrefHi + (size_t)B * NC1 * D;
  float* ScalHi = ScalLo + (size_t)B * NC1;

  hipMemsetAsync(rank, 0, (size_t)BN * sizeof(int), stream);
  k_f1f2<<<dim3(BN/4), 256, 0, stream>>>(seq, w1, b1, w2, b2, f1, f2);
  k_rank_count<<<dim3(N/1024, N/256, B), 256, 0, stream>>>(f2, rank);
  k_scatter<<<dim3(BN/256), 256, 0, stream>>>(f2, rank, sF2, sIdx, e2lo, e2hi);
  k_gemm<<<dim3(N/64, D/64, B), 256, 0, stream>>>(seq, Wf, sIdx, Vs);
  k_chunks<<<dim3(NC, B), 256, 0, stream>>>(Vs, e2lo, e2hi, PrefLo, PrefHi, ScalLo, ScalHi);
  k_scan<<<dim3(B), 256, 0, stream>>>(PrefLo, PrefHi, ScalLo, ScalHi);
  k_combine<<<dim3(N/4, B), 256, 0, stream>>>(f1, sF2, e2lo, e2hi, Vs,
      PrefLo, PrefHi, ScalLo, ScalHi, bias, out);
}

// Round 3
// 139.006 us; speedup vs baseline: 2.0181x; 1.4084x over previous
//
#include <hip/hip_runtime.h>
#include <hip/hip_bf16.h>
#include <math.h>

#define B 8
#define N 4096
#define D 256
#define BN (B*N)
#define L 8
#define NC (N/L)      // 512 chunks per batch
#define NC1 (NC+1)    // 513
#define NSUP 64       // superchunks (8 chunks each)

typedef __attribute__((ext_vector_type(8))) short bf16x8;
typedef __attribute__((ext_vector_type(4))) float f32x4;

#define GLD16(src, dst) __builtin_amdgcn_global_load_lds( \
    (const __attribute__((address_space(1))) void*)(src), \
    (__attribute__((address_space(3))) void*)(dst), 16, 0, 0)

// ---------------- K1: f1 = seq@w1 + b1, f2 = seq@w2 + b2 (one wave per row) ----
__global__ __launch_bounds__(256) void k_f1f2(const float* __restrict__ seq,
    const float* __restrict__ w1, const float* __restrict__ b1,
    const float* __restrict__ w2, const float* __restrict__ b2,
    float* __restrict__ f1, float* __restrict__ f2) {
  int wave = threadIdx.x >> 6;
  int lane = threadIdx.x & 63;
  long row = (long)blockIdx.x * 4 + wave;
  float4 v = ((const float4*)(seq + row * D))[lane];
  float4 a = ((const float4*)w1)[lane];
  float4 b = ((const float4*)w2)[lane];
  float s1 = v.x*a.x + v.y*a.y + v.z*a.z + v.w*a.w;
  float s2 = v.x*b.x + v.y*b.y + v.z*b.z + v.w*b.w;
  for (int off = 32; off; off >>= 1) {
    s1 += __shfl_xor(s1, off, 64);
    s2 += __shfl_xor(s2, off, 64);
  }
  if (lane == 0) { f1[row] = s1 + b1[0]; f2[row] = s2 + b2[0]; }
}

// ---------------- K2a: partial rank counts (tiled O(N^2), 64-bit keys) ---------
__global__ __launch_bounds__(256) void k_rank_count(const float* __restrict__ f2,
    int* __restrict__ rank) {
  __shared__ unsigned long long skey[256];
  int b = blockIdx.z;
  int tid = threadIdx.x;
  const float* fb = f2 + (long)b * N;
  int p = blockIdx.y * 256 + tid;
  unsigned int up = __float_as_uint(fb[p]);
  up ^= (unsigned int)(((int)up >> 31) | 0x80000000);
  skey[tid] = ((unsigned long long)up << 12) | (unsigned)p;
  unsigned long long kj[4];
  int jbase = blockIdx.x * 1024;
  #pragma unroll
  for (int q = 0; q < 4; ++q) {
    int j = jbase + q * 256 + tid;
    unsigned int uj = __float_as_uint(fb[j]);
    uj ^= (unsigned int)(((int)uj >> 31) | 0x80000000);
    kj[q] = ((unsigned long long)uj << 12) | (unsigned)j;
  }
  __syncthreads();
  int c[4] = {0, 0, 0, 0};
  const ulonglong2* sk2 = (const ulonglong2*)skey;
  #pragma unroll 4
  for (int pp = 0; pp < 128; ++pp) {
    ulonglong2 kk = sk2[pp];
    #pragma unroll
    for (int q = 0; q < 4; ++q) {
      c[q] += (kk.x < kj[q]) ? 1 : 0;
      c[q] += (kk.y < kj[q]) ? 1 : 0;
    }
  }
  #pragma unroll
  for (int q = 0; q < 4; ++q)
    atomicAdd(&rank[(long)b * N + jbase + q * 256 + tid], c[q]);
}

// ---------------- K2b: scatter into sorted order -------------------------------
__global__ __launch_bounds__(256) void k_scatter(const float* __restrict__ f2,
    const int* __restrict__ rank, float* __restrict__ sF2, int* __restrict__ sIdx,
    float* __restrict__ e2lo, float* __restrict__ e2hi) {
  long idx = (long)blockIdx.x * 256 + threadIdx.x;
  int b = (int)(idx >> 12);
  int j = (int)(idx & (N - 1));
  float v = f2[idx];
  int cnt = rank[idx];
  long o = (long)b * N + cnt;
  sF2[o] = v;
  sIdx[o] = j;
  e2lo[o] = expf(0.01f * v);
  e2hi[o] = expf(v);
}

// ---------------- K2c: split gathered seq rows into bf16 hi|lo -----------------
__global__ __launch_bounds__(256) void k_split(const float* __restrict__ seq,
    const int* __restrict__ sIdx, ushort* __restrict__ A2) {
  int wid = threadIdx.x >> 6, lane = threadIdx.x & 63;
  size_t p = (size_t)blockIdx.x * 4 + wid;
  int b = (int)(p >> 12);
  int j = sIdx[p];
  float4 v = ((const float4*)(seq + (((size_t)b << 12) + j) * D))[lane];
  float xs[4] = {v.x, v.y, v.z, v.w};
  ushort hu[4], lu[4];
  #pragma unroll
  for (int c = 0; c < 4; ++c) {
    __hip_bfloat16 hb = __float2bfloat16(xs[c]);
    float hf = __bfloat162float(hb);
    __hip_bfloat16 lb = __float2bfloat16(xs[c] - hf);
    hu[c] = *(ushort*)&hb; lu[c] = *(ushort*)&lb;
  }
  *(ushort4*)(A2 + (p << 9) + lane * 4) = make_ushort4(hu[0], hu[1], hu[2], hu[3]);
  *(ushort4*)(A2 + (p << 9) + 256 + lane * 4) = make_ushort4(lu[0], lu[1], lu[2], lu[3]);
}

// ---------------- K2d: W -> W3t[n][768] = [Wh | Wl | Wh] (transposed) ----------
__global__ __launch_bounds__(256) void k_wsplit(const float* __restrict__ W,
    ushort* __restrict__ W3) {
  int n = blockIdx.x;
  int k = threadIdx.x;
  float x = W[(size_t)k * D + n];
  __hip_bfloat16 h = __float2bfloat16(x);
  float hf = __bfloat162float(h);
  __hip_bfloat16 l = __float2bfloat16(x - hf);
  ushort hu = *(ushort*)&h, lu = *(ushort*)&l;
  W3[(size_t)n * 768 + k] = hu;
  W3[(size_t)n * 768 + 256 + k] = lu;
  W3[(size_t)n * 768 + 512 + k] = hu;
}

// ---------------- K3: Vs = A2(split) @ W3(split), bf16 MFMA, K=768 -------------
// tile 64(M) x 256(N), BK=64, 4 waves (2x2), each wave 32x128 (2x8 16x16 frags)
__global__ __launch_bounds__(256) void k_mfma(const ushort* __restrict__ A2,
    const ushort* __restrict__ W3, float* __restrict__ Vs) {
  __shared__ __align__(16) ushort As[64][64];
  __shared__ __align__(16) ushort Bs[256][64];
  int tid = threadIdx.x;
  int wid = tid >> 6, lane = tid & 63;
  int mBase = blockIdx.x * 64;
  int lr = lane >> 3;
  int lc = (lane & 7) * 8;
  int wr = wid >> 1, wc = wid & 1;
  int g = lane >> 4, r16 = lane & 15;

  f32x4 acc[2][8];
  #pragma unroll
  for (int m = 0; m < 2; ++m)
    #pragma unroll
    for (int n = 0; n < 8; ++n) {
      acc[m][n][0] = 0.f; acc[m][n][1] = 0.f; acc[m][n][2] = 0.f; acc[m][n][3] = 0.f;
    }

  for (int kt = 0; kt < 768; kt += 64) {
    int seg = kt >> 8;
    int aoff = ((seg == 2) ? 256 : 0) + (kt & 255);
    __syncthreads();
    #pragma unroll
    for (int q = 0; q < 2; ++q) {
      int r0 = q * 32 + wid * 8;
      GLD16(A2 + (((size_t)(mBase + r0 + lr)) << 9) + aoff + lc, &As[r0][0]);
    }
    #pragma unroll
    for (int q = 0; q < 8; ++q) {
      int r0 = q * 32 + wid * 8;
      GLD16(W3 + (size_t)(r0 + lr) * 768 + kt + lc, &Bs[r0][0]);
    }
    __syncthreads();
    #pragma unroll
    for (int kk = 0; kk < 64; kk += 32) {
      bf16x8 av[2], bv[8];
      #pragma unroll
      for (int m = 0; m < 2; ++m)
        av[m] = *(const bf16x8*)&As[wr*32 + m*16 + r16][kk + g*8];
      #pragma unroll
      for (int n = 0; n < 8; ++n)
        bv[n] = *(const bf16x8*)&Bs[wc*128 + n*16 + r16][kk + g*8];
      #pragma unroll
      for (int m = 0; m < 2; ++m)
        #pragma unroll
        for (int n = 0; n < 8; ++n)
          acc[m][n] = __builtin_amdgcn_mfma_f32_16x16x32_bf16(av[m], bv[n], acc[m][n], 0, 0, 0);
    }
  }
  #pragma unroll
  for (int m = 0; m < 2; ++m)
    #pragma unroll
    for (int n = 0; n < 8; ++n) {
      int col = wc*128 + n*16 + r16;
      #pragma unroll
      for (int j = 0; j < 4; ++j) {
        int row = mBase + wr*32 + m*16 + g*4 + j;
        Vs[(size_t)row * D + col] = acc[m][n][j];
      }
    }
}

// ---------------- K4a: per-chunk weighted sums (L=8) ---------------------------
__global__ __launch_bounds__(256) void k_chunks(const float* __restrict__ Vs,
    const float* __restrict__ e2lo, const float* __restrict__ e2hi,
    float* __restrict__ PrefLo, float* __restrict__ PrefHi,
    float* __restrict__ ScalLo, float* __restrict__ ScalHi) {
  int c = blockIdx.x, b = blockIdx.y, d = threadIdx.x;
  long base = (long)b * N + c * L;
  float alo = 0.f, ahi = 0.f, slo = 0.f, shi = 0.f;
  #pragma unroll
  for (int r = 0; r < L; ++r) {
    float wlo = e2lo[base + r], whi = e2hi[base + r];
    float v = Vs[(base + r) * D + d];
    alo += wlo * v; ahi += whi * v;
    slo += wlo;     shi += whi;
  }
  PrefLo[((long)b * NC1 + c) * D + d] = alo;
  PrefHi[((long)b * NC1 + c) * D + d] = ahi;
  if (d == 0) { ScalLo[b * NC1 + c] = slo; ScalHi[b * NC1 + c] = shi; }
}

// ---------------- K4b: superchunk sums (8 chunks each) -------------------------
__global__ __launch_bounds__(256) void k_sup(const float* __restrict__ PrefLo,
    const float* __restrict__ PrefHi, float* __restrict__ SupLo,
    float* __restrict__ SupHi) {
  int s = blockIdx.x, b = blockIdx.y, d = threadIdx.x;
  float alo = 0.f, ahi = 0.f;
  #pragma unroll
  for (int u = 0; u < 8; ++u) {
    size_t o = ((size_t)b * NC1 + s * 8 + u) * D + d;
    alo += PrefLo[o]; ahi += PrefHi[o];
  }
  SupLo[((size_t)b * NSUP + s) * D + d] = alo;
  SupHi[((size_t)b * NSUP + s) * D + d] = ahi;
}

// ---------------- K4c: exclusive scan over 64 supers; writes total row ---------
__global__ __launch_bounds__(256) void k_supscan(float* __restrict__ SupLo,
    float* __restrict__ SupHi, float* __restrict__ PrefLo, float* __restrict__ PrefHi) {
  int b = blockIdx.x, d = threadIdx.x;
  size_t base = ((size_t)b * NSUP) * D + d;
  float runLo = 0.f, runHi = 0.f;
  for (int sb = 0; sb < NSUP; sb += 8) {
    float tl[8], th[8];
    #pragma unroll
    for (int u = 0; u < 8; ++u) {
      size_t o = base + (size_t)(sb + u) * D;
      tl[u] = SupLo[o]; th[u] = SupHi[o];
    }
    #pragma unroll
    for (int u = 0; u < 8; ++u) {
      size_t o = base + (size_t)(sb + u) * D;
      SupLo[o] = runLo; SupHi[o] = runHi;
      runLo += tl[u]; runHi += th[u];
    }
  }
  PrefLo[((size_t)b * NC1 + NC) * D + d] = runLo;
  PrefHi[((size_t)b * NC1 + NC) * D + d] = runHi;
}

// ---------------- K4d: per-super exclusive scan of its 8 chunks ----------------
__global__ __launch_bounds__(256) void k_chunkscan(const float* __restrict__ SupLo,
    const float* __restrict__ SupHi, float* __restrict__ PrefLo,
    float* __restrict__ PrefHi) {
  int s = blockIdx.x, b = blockIdx.y, d = threadIdx.x;
  float runLo = SupLo[((size_t)b * NSUP + s) * D + d];
  float runHi = SupHi[((size_t)b * NSUP + s) * D + d];
  size_t base = ((size_t)b * NC1 + s * 8) * D + d;
  float tl[8], th[8];
  #pragma unroll
  for (int u = 0; u < 8; ++u) {
    tl[u] = PrefLo[base + (size_t)u * D];
    th[u] = PrefHi[base + (size_t)u * D];
  }
  #pragma unroll
  for (int u = 0; u < 8; ++u) {
    PrefLo[base + (size_t)u * D] = runLo; runLo += tl[u];
    PrefHi[base + (size_t)u * D] = runHi; runHi += th[u];
  }
}

// ---------------- K4e: LDS Hillis-Steele scan for scalar sums ------------------
__global__ __launch_bounds__(512) void k_scalscan(float* __restrict__ ScalLo,
    float* __restrict__ ScalHi) {
  __shared__ float slo[NC], shi[NC];
  int b = blockIdx.x, t = threadIdx.x;
  float vlo = ScalLo[b * NC1 + t], vhi = ScalHi[b * NC1 + t];
  slo[t] = vlo; shi[t] = vhi;
  __syncthreads();
  for (int off = 1; off < NC; off <<= 1) {
    float alo = (t >= off) ? slo[t - off] : 0.f;
    float ahi = (t >= off) ? shi[t - off] : 0.f;
    __syncthreads();
    slo[t] += alo; shi[t] += ahi;
    __syncthreads();
  }
  ScalLo[b * NC1 + t] = slo[t] - vlo;
  ScalHi[b * NC1 + t] = shi[t] - vhi;
  if (t == NC - 1) {
    ScalLo[b * NC1 + NC] = slo[t];
    ScalHi[b * NC1 + NC] = shi[t];
  }
}

// ---------------- K5a: threshold rank per row (LDS binary search) --------------
__global__ __launch_bounds__(256) void k_findk(const float* __restrict__ f1,
    const float* __restrict__ sF2, int* __restrict__ kArr) {
  __shared__ float sf[N];
  int b = blockIdx.y;
  for (int t = threadIdx.x; t < N; t += 256) sf[t] = sF2[((size_t)b << 12) + t];
  __syncthreads();
  int i = blockIdx.x * 256 + threadIdx.x;
  float t = -f1[((size_t)b << 12) + i];
  int lo = 0, hi = N;
  while (lo < hi) { int mid = (lo + hi) >> 1; if (sf[mid] <= t) lo = mid + 1; else hi = mid; }
  kArr[((size_t)b << 12) + i] = lo;
}

// ---------------- K5b: combine (streaming, branchless residual) ----------------
__global__ __launch_bounds__(256) void k_combine(const float* __restrict__ f1,
    const int* __restrict__ kArr, const float* __restrict__ e2lo,
    const float* __restrict__ e2hi, const float* __restrict__ Vs,
    const float* __restrict__ PrefLo, const float* __restrict__ PrefHi,
    const float* __restrict__ ScalLo, const float* __restrict__ ScalHi,
    const float* __restrict__ bias, float* __restrict__ out) {
  size_t i = blockIdx.x;
  int b = (int)(i >> 12);
  int d = threadIdx.x;
  float f1v = f1[i];
  int k = kArr[i];
  float a = expf(f1v), cc = expf(0.01f * f1v);
  int c0 = k >> 3;
  size_t pb = ((size_t)b * NC1 + c0) * D + d;
  size_t pt = ((size_t)b * NC1 + NC) * D + d;
  float plo = PrefLo[pb], phiB = PrefHi[pb], phiT = PrefHi[pt];
  int rbase = c0 * L;
  float resLo = 0.f, resHi = 0.f, szLo = 0.f, szHi = 0.f;
  #pragma unroll
  for (int r = 0; r < L; ++r) {
    int rr = rbase + r;
    float msk = (rr < k) ? 1.f : 0.f;
    int rc = rr < N ? rr : N - 1;
    size_t o = ((size_t)b << 12) + rc;
    float wlo = e2lo[o] * msk, whi = e2hi[o] * msk;
    float v = Vs[o * D + d];
    resLo += wlo * v; resHi += whi * v;
    szLo += wlo;      szHi += whi;
  }
  float Slo = plo + resLo;
  float Shi = phiT - phiB - resHi;
  float Zlo = ScalLo[b * NC1 + c0] + szLo;
  float Zhi = ScalHi[b * NC1 + NC] - ScalHi[b * NC1 + c0] - szHi;
  float Z = a * Zhi + cc * Zlo;
  float o = (a * Shi + cc * Slo) / Z + bias[0];
  out[i * D + d] = fmaxf(o, 0.f);
}

// ---------------- launch -------------------------------------------------------
extern "C" void kernel_launch(void* const* d_in, const int* in_sizes, int n_in,
                              void* d_out, int out_size, void* d_ws, size_t ws_size,
                              hipStream_t stream) {
  const float* seq  = (const float*)d_in[0];
  const float* Wf   = (const float*)d_in[1];
  const float* w1   = (const float*)d_in[2];
  const float* b1   = (const float*)d_in[3];
  const float* w2   = (const float*)d_in[4];
  const float* b2   = (const float*)d_in[5];
  const float* bias = (const float*)d_in[6];
  float* out = (float*)d_out;

  // ws layout: scalars | Vs | union(A2 | scan arrays) | W3
  size_t need = (size_t)8 * BN * 4                // f1,f2,sF2,e2lo,e2hi,sIdx,rank,kArr
              + (size_t)BN * D * 4                // Vs
              + (size_t)BN * 512 * 2              // A2 (unioned with scan arrays)
              + (size_t)256 * 768 * 2;            // W3
  if (ws_size < need) return;

  float* f1   = (float*)d_ws;
  float* f2   = f1 + BN;
  float* sF2  = f2 + BN;
  float* e2lo = sF2 + BN;
  float* e2hi = e2lo + BN;
  int* sIdx   = (int*)(e2hi + BN);
  int* rank   = sIdx + BN;
  int* kArr   = rank + BN;
  float* Vs   = (float*)(kArr + BN);
  char* uni   = (char*)(Vs + (size_t)BN * D);
  ushort* A2  = (ushort*)uni;
  float* PrefLo = (float*)uni;                            // aliases A2 (A2 dead post-mfma)
  float* PrefHi = PrefLo + (size_t)B * NC1 * D;
  float* SupLo  = PrefHi + (size_t)B * NC1 * D;
  float* SupHi  = SupLo + (size_t)B * NSUP * D;
  float* ScalLo = SupHi + (size_t)B * NSUP * D;
  float* ScalHi = ScalLo + (size_t)B * NC1;
  ushort* W3  = (ushort*)(uni + (size_t)BN * 512 * 2);

  hipMemsetAsync(rank, 0, (size_t)BN * sizeof(int), stream);
  k_f1f2<<<dim3(BN/4), 256, 0, stream>>>(seq, w1, b1, w2, b2, f1, f2);
  k_wsplit<<<dim3(256), 256, 0, stream>>>(Wf, W3);
  k_rank_count<<<dim3(N/1024, N/256, B), 256, 0, stream>>>(f2, rank);
  k_scatter<<<dim3(BN/256), 256, 0, stream>>>(f2, rank, sF2, sIdx, e2lo, e2hi);
  k_split<<<dim3(BN/4), 256, 0, stream>>>(seq, sIdx, A2);
  k_mfma<<<dim3(BN/64), 256, 0, stream>>>(A2, W3, Vs);
  k_chunks<<<dim3(NC, B), 256, 0, stream>>>(Vs, e2lo, e2hi, PrefLo, PrefHi, ScalLo, ScalHi);
  k_sup<<<dim3(NSUP, B), 256, 0, stream>>>(PrefLo, PrefHi, SupLo, SupHi);
  k_supscan<<<dim3(B), 256, 0, stream>>>(SupLo, SupHi, PrefLo, PrefHi);
  k_chunkscan<<<dim3(NSUP, B), 256, 0, stream>>>(SupLo, SupHi, PrefLo, PrefHi);
  k_scalscan<<<dim3(B), 512, 0, stream>>>(ScalLo, ScalHi);
  k_findk<<<dim3(N/256, B), 256, 0, stream>>>(f1, sF2, kArr);
  k_combine<<<dim3(BN), 256, 0, stream>>>(f1, kArr, e2lo, e2hi, Vs,
      PrefLo, PrefHi, ScalLo, ScalHi, bias, out);
}

// Round 4
// 135.960 us; speedup vs baseline: 2.0633x; 1.0224x over previous
//
#include <hip/hip_runtime.h>
#include <hip/hip_bf16.h>
#include <math.h>

#define B 8
#define N 4096
#define D 256
#define BN (B*N)
#define NSUP 64       // 64-row superchunks per batch
#define NP4 1025      // vector prefix rows per batch (every 4th pos + total)
#define NZ 4097       // scalar prefix entries per batch (every pos + total)

typedef __attribute__((ext_vector_type(8))) short bf16x8;
typedef __attribute__((ext_vector_type(4))) float f32x4;

#define GLD16(src, dst) __builtin_amdgcn_global_load_lds( \
    (const __attribute__((address_space(1))) void*)(src), \
    (__attribute__((address_space(3))) void*)(dst), 16, 0, 0)

// ---------------- K1: f1 = seq@w1 + b1, f2 = seq@w2 + b2 (one wave per row) ----
__global__ __launch_bounds__(256) void k_f1f2(const float* __restrict__ seq,
    const float* __restrict__ w1, const float* __restrict__ b1,
    const float* __restrict__ w2, const float* __restrict__ b2,
    float* __restrict__ f1, float* __restrict__ f2) {
  int wave = threadIdx.x >> 6;
  int lane = threadIdx.x & 63;
  long row = (long)blockIdx.x * 4 + wave;
  float4 v = ((const float4*)(seq + row * D))[lane];
  float4 a = ((const float4*)w1)[lane];
  float4 b = ((const float4*)w2)[lane];
  float s1 = v.x*a.x + v.y*a.y + v.z*a.z + v.w*a.w;
  float s2 = v.x*b.x + v.y*b.y + v.z*b.z + v.w*b.w;
  for (int off = 32; off; off >>= 1) {
    s1 += __shfl_xor(s1, off, 64);
    s2 += __shfl_xor(s2, off, 64);
  }
  if (lane == 0) { f1[row] = s1 + b1[0]; f2[row] = s2 + b2[0]; }
}

// ---------------- K2a: partial rank counts (tiled O(N^2), 64-bit keys) ---------
__global__ __launch_bounds__(256) void k_rank_count(const float* __restrict__ f2,
    int* __restrict__ rank) {
  __shared__ unsigned long long skey[256];
  int b = blockIdx.z;
  int tid = threadIdx.x;
  const float* fb = f2 + (long)b * N;
  int p = blockIdx.y * 256 + tid;
  unsigned int up = __float_as_uint(fb[p]);
  up ^= (unsigned int)(((int)up >> 31) | 0x80000000);
  skey[tid] = ((unsigned long long)up << 12) | (unsigned)p;
  unsigned long long kj[4];
  int jbase = blockIdx.x * 1024;
  #pragma unroll
  for (int q = 0; q < 4; ++q) {
    int j = jbase + q * 256 + tid;
    unsigned int uj = __float_as_uint(fb[j]);
    uj ^= (unsigned int)(((int)uj >> 31) | 0x80000000);
    kj[q] = ((unsigned long long)uj << 12) | (unsigned)j;
  }
  __syncthreads();
  int c[4] = {0, 0, 0, 0};
  const ulonglong2* sk2 = (const ulonglong2*)skey;
  #pragma unroll 4
  for (int pp = 0; pp < 128; ++pp) {
    ulonglong2 kk = sk2[pp];
    #pragma unroll
    for (int q = 0; q < 4; ++q) {
      c[q] += (kk.x < kj[q]) ? 1 : 0;
      c[q] += (kk.y < kj[q]) ? 1 : 0;
    }
  }
  #pragma unroll
  for (int q = 0; q < 4; ++q)
    atomicAdd(&rank[(long)b * N + jbase + q * 256 + tid], c[q]);
}

// ---------------- K2b: scatter into sorted order -------------------------------
__global__ __launch_bounds__(256) void k_scatter(const float* __restrict__ f2,
    const int* __restrict__ rank, float* __restrict__ sF2, int* __restrict__ sIdx,
    float* __restrict__ e2lo, float* __restrict__ e2hi) {
  long idx = (long)blockIdx.x * 256 + threadIdx.x;
  int b = (int)(idx >> 12);
  int j = (int)(idx & (N - 1));
  float v = f2[idx];
  int cnt = rank[idx];
  long o = (long)b * N + cnt;
  sF2[o] = v;
  sIdx[o] = j;
  e2lo[o] = expf(0.01f * v);
  e2hi[o] = expf(v);
}

// ---------------- K2c: split gathered seq rows into bf16 hi|lo -----------------
__global__ __launch_bounds__(256) void k_split(const float* __restrict__ seq,
    const int* __restrict__ sIdx, ushort* __restrict__ A2) {
  int wid = threadIdx.x >> 6, lane = threadIdx.x & 63;
  size_t p = (size_t)blockIdx.x * 4 + wid;
  int b = (int)(p >> 12);
  int j = sIdx[p];
  float4 v = ((const float4*)(seq + (((size_t)b << 12) + j) * D))[lane];
  float xs[4] = {v.x, v.y, v.z, v.w};
  ushort hu[4], lu[4];
  #pragma unroll
  for (int c = 0; c < 4; ++c) {
    __hip_bfloat16 hb = __float2bfloat16(xs[c]);
    float hf = __bfloat162float(hb);
    __hip_bfloat16 lb = __float2bfloat16(xs[c] - hf);
    hu[c] = *(ushort*)&hb; lu[c] = *(ushort*)&lb;
  }
  *(ushort4*)(A2 + (p << 9) + lane * 4) = make_ushort4(hu[0], hu[1], hu[2], hu[3]);
  *(ushort4*)(A2 + (p << 9) + 256 + lane * 4) = make_ushort4(lu[0], lu[1], lu[2], lu[3]);
}

// ---------------- K2d: W -> W3t[n][768] = [Wh | Wl | Wh] (transposed) ----------
__global__ __launch_bounds__(256) void k_wsplit(const float* __restrict__ W,
    ushort* __restrict__ W3) {
  int n = blockIdx.x;
  int k = threadIdx.x;
  float x = W[(size_t)k * D + n];
  __hip_bfloat16 h = __float2bfloat16(x);
  float hf = __bfloat162float(h);
  __hip_bfloat16 l = __float2bfloat16(x - hf);
  ushort hu = *(ushort*)&h, lu = *(ushort*)&l;
  W3[(size_t)n * 768 + k] = hu;
  W3[(size_t)n * 768 + 256 + k] = lu;
  W3[(size_t)n * 768 + 512 + k] = hu;
}

// ---------------- K3: Vs = A2(split) @ W3(split), bf16 MFMA, K=768 -------------
__global__ __launch_bounds__(256) void k_mfma(const ushort* __restrict__ A2,
    const ushort* __restrict__ W3, float* __restrict__ Vs) {
  __shared__ __align__(16) ushort As[64][64];
  __shared__ __align__(16) ushort Bs[256][64];
  int tid = threadIdx.x;
  int wid = tid >> 6, lane = tid & 63;
  int mBase = blockIdx.x * 64;
  int lr = lane >> 3;
  int lc = (lane & 7) * 8;
  int wr = wid >> 1, wc = wid & 1;
  int g = lane >> 4, r16 = lane & 15;

  f32x4 acc[2][8];
  #pragma unroll
  for (int m = 0; m < 2; ++m)
    #pragma unroll
    for (int n = 0; n < 8; ++n) {
      acc[m][n][0] = 0.f; acc[m][n][1] = 0.f; acc[m][n][2] = 0.f; acc[m][n][3] = 0.f;
    }

  for (int kt = 0; kt < 768; kt += 64) {
    int seg = kt >> 8;
    int aoff = ((seg == 2) ? 256 : 0) + (kt & 255);
    __syncthreads();
    #pragma unroll
    for (int q = 0; q < 2; ++q) {
      int r0 = q * 32 + wid * 8;
      GLD16(A2 + (((size_t)(mBase + r0 + lr)) << 9) + aoff + lc, &As[r0][0]);
    }
    #pragma unroll
    for (int q = 0; q < 8; ++q) {
      int r0 = q * 32 + wid * 8;
      GLD16(W3 + (size_t)(r0 + lr) * 768 + kt + lc, &Bs[r0][0]);
    }
    __syncthreads();
    #pragma unroll
    for (int kk = 0; kk < 64; kk += 32) {
      bf16x8 av[2], bv[8];
      #pragma unroll
      for (int m = 0; m < 2; ++m)
        av[m] = *(const bf16x8*)&As[wr*32 + m*16 + r16][kk + g*8];
      #pragma unroll
      for (int n = 0; n < 8; ++n)
        bv[n] = *(const bf16x8*)&Bs[wc*128 + n*16 + r16][kk + g*8];
      #pragma unroll
      for (int m = 0; m < 2; ++m)
        #pragma unroll
        for (int n = 0; n < 8; ++n)
          acc[m][n] = __builtin_amdgcn_mfma_f32_16x16x32_bf16(av[m], bv[n], acc[m][n], 0, 0, 0);
    }
  }
  #pragma unroll
  for (int m = 0; m < 2; ++m)
    #pragma unroll
    for (int n = 0; n < 8; ++n) {
      int col = wc*128 + n*16 + r16;
      #pragma unroll
      for (int j = 0; j < 4; ++j) {
        int row = mBase + wr*32 + m*16 + g*4 + j;
        Vs[(size_t)row * D + col] = acc[m][n][j];
      }
    }
}

// ---------------- K4a: per-super (64 rows) weighted sums, float4 ---------------
__global__ __launch_bounds__(256) void k_supstats(const float* __restrict__ Vs,
    const float* __restrict__ e2lo, const float* __restrict__ e2hi,
    float* __restrict__ SupLo, float* __restrict__ SupHi,
    float* __restrict__ SupZlo, float* __restrict__ SupZhi) {
  int wid = threadIdx.x >> 6, lane = threadIdx.x & 63;
  int s = blockIdx.x * 4 + wid;
  int b = blockIdx.y;
  size_t rbase = ((size_t)b << 12) + (size_t)s * 64;
  const float4* vsrc = (const float4*)Vs + rbase * 64 + lane;
  float4 alo = {0,0,0,0}, ahi = {0,0,0,0};
  float zlo = 0.f, zhi = 0.f;
  #pragma unroll 8
  for (int r = 0; r < 64; ++r) {
    float wlo = e2lo[rbase + r], whi = e2hi[rbase + r];
    float4 v = vsrc[(size_t)r * 64];
    alo.x += wlo*v.x; alo.y += wlo*v.y; alo.z += wlo*v.z; alo.w += wlo*v.w;
    ahi.x += whi*v.x; ahi.y += whi*v.y; ahi.z += whi*v.z; ahi.w += whi*v.w;
    zlo += wlo; zhi += whi;
  }
  ((float4*)SupLo)[((size_t)b * NSUP + s) * 64 + lane] = alo;
  ((float4*)SupHi)[((size_t)b * NSUP + s) * 64 + lane] = ahi;
  if (lane == 0) { SupZlo[b*NSUP+s] = zlo; SupZhi[b*NSUP+s] = zhi; }
}

// ---------------- K4b: exclusive scan over 64 supers + totals ------------------
__global__ __launch_bounds__(256) void k_supscan(float* __restrict__ SupLo,
    float* __restrict__ SupHi, float* __restrict__ SupZlo, float* __restrict__ SupZhi,
    float* __restrict__ PrefLo, float* __restrict__ PrefHi,
    float* __restrict__ ZloArr, float* __restrict__ ZhiArr) {
  int b = blockIdx.x, t = threadIdx.x;
  if (t < 64) {
    float4* lo = (float4*)SupLo + (size_t)b * NSUP * 64 + t;
    float4* hi = (float4*)SupHi + (size_t)b * NSUP * 64 + t;
    float4 rl = {0,0,0,0}, rh = {0,0,0,0};
    for (int s = 0; s < NSUP; s += 8) {
      float4 tl[8], th[8];
      #pragma unroll
      for (int u = 0; u < 8; ++u) { tl[u] = lo[(size_t)(s+u)*64]; th[u] = hi[(size_t)(s+u)*64]; }
      #pragma unroll
      for (int u = 0; u < 8; ++u) {
        lo[(size_t)(s+u)*64] = rl; hi[(size_t)(s+u)*64] = rh;
        rl.x+=tl[u].x; rl.y+=tl[u].y; rl.z+=tl[u].z; rl.w+=tl[u].w;
        rh.x+=th[u].x; rh.y+=th[u].y; rh.z+=th[u].z; rh.w+=th[u].w;
      }
    }
    ((float4*)PrefLo)[((size_t)b * NP4 + 1024) * 64 + t] = rl;
    ((float4*)PrefHi)[((size_t)b * NP4 + 1024) * 64 + t] = rh;
  } else if (t == 64) {
    float r = 0.f;
    for (int s = 0; s < NSUP; ++s) { float x = SupZlo[b*NSUP+s]; SupZlo[b*NSUP+s] = r; r += x; }
    ZloArr[(size_t)b * NZ + 4096] = r;
  } else if (t == 65) {
    float r = 0.f;
    for (int s = 0; s < NSUP; ++s) { float x = SupZhi[b*NSUP+s]; SupZhi[b*NSUP+s] = r; r += x; }
    ZhiArr[(size_t)b * NZ + 4096] = r;
  }
}

// ---------------- K4c: write gran-4 vector prefix + gran-1 scalar prefix -------
__global__ __launch_bounds__(256) void k_prefwrite(const float* __restrict__ Vs,
    const float* __restrict__ e2lo, const float* __restrict__ e2hi,
    const float* __restrict__ SupLo, const float* __restrict__ SupHi,
    const float* __restrict__ SupZlo, const float* __restrict__ SupZhi,
    float* __restrict__ PrefLo, float* __restrict__ PrefHi,
    float* __restrict__ ZloArr, float* __restrict__ ZhiArr) {
  int wid = threadIdx.x >> 6, lane = threadIdx.x & 63;
  int s = blockIdx.x * 4 + wid;
  int b = blockIdx.y;
  size_t rbase = ((size_t)b << 12) + (size_t)s * 64;
  const float4* vsrc = (const float4*)Vs + rbase * 64 + lane;
  float4 rl = ((const float4*)SupLo)[((size_t)b * NSUP + s) * 64 + lane];
  float4 rh = ((const float4*)SupHi)[((size_t)b * NSUP + s) * 64 + lane];
  float zlo = SupZlo[b*NSUP+s], zhi = SupZhi[b*NSUP+s];
  float4* plo = (float4*)PrefLo + ((size_t)b * NP4 + s * 16) * 64 + lane;
  float4* phi = (float4*)PrefHi + ((size_t)b * NP4 + s * 16) * 64 + lane;
  float* zl = ZloArr + (size_t)b * NZ + s * 64;
  float* zh = ZhiArr + (size_t)b * NZ + s * 64;
  #pragma unroll 4
  for (int r = 0; r < 64; ++r) {
    float wlo = e2lo[rbase + r], whi = e2hi[rbase + r];
    float4 v = vsrc[(size_t)r * 64];
    if ((r & 3) == 0) { plo[(size_t)(r>>2) * 64] = rl; phi[(size_t)(r>>2) * 64] = rh; }
    if (lane == 0) { zl[r] = zlo; zh[r] = zhi; }
    rl.x += wlo*v.x; rl.y += wlo*v.y; rl.z += wlo*v.z; rl.w += wlo*v.w;
    rh.x += whi*v.x; rh.y += whi*v.y; rh.z += whi*v.z; rh.w += whi*v.w;
    zlo += wlo; zhi += whi;
  }
}

// ---------------- K5a: threshold rank per row (LDS binary search) --------------
__global__ __launch_bounds__(256) void k_findk(const float* __restrict__ f1,
    const float* __restrict__ sF2, int* __restrict__ kArr) {
  __shared__ float sf[N];
  int b = blockIdx.y;
  for (int t = threadIdx.x; t < N; t += 256) sf[t] = sF2[((size_t)b << 12) + t];
  __syncthreads();
  int i = blockIdx.x * 256 + threadIdx.x;
  float t = -f1[((size_t)b << 12) + i];
  int lo = 0, hi = N;
  while (lo < hi) { int mid = (lo + hi) >> 1; if (sf[mid] <= t) lo = mid + 1; else hi = mid; }
  kArr[((size_t)b << 12) + i] = lo;
}

// ---------------- K5b: combine (1 wave/row, float4, <=3-row residual) ----------
__global__ __launch_bounds__(256) void k_combine2(const float* __restrict__ f1,
    const int* __restrict__ kArr, const float* __restrict__ e2lo,
    const float* __restrict__ e2hi, const float* __restrict__ Vs,
    const float* __restrict__ PrefLo, const float* __restrict__ PrefHi,
    const float* __restrict__ ZloArr, const float* __restrict__ ZhiArr,
    const float* __restrict__ bias, float* __restrict__ out) {
  int wid = threadIdx.x >> 6, lane = threadIdx.x & 63;
  size_t i = (size_t)blockIdx.x * 4 + wid;
  int b = (int)(i >> 12);
  float f1v = f1[i];
  int k = kArr[i];
  float a = expf(f1v), cc = expf(0.01f * f1v);
  int m = k >> 2;
  float4 plo = ((const float4*)PrefLo)[((size_t)b * NP4 + m) * 64 + lane];
  float4 phb = ((const float4*)PrefHi)[((size_t)b * NP4 + m) * 64 + lane];
  float4 pht = ((const float4*)PrefHi)[((size_t)b * NP4 + 1024) * 64 + lane];
  float Zlo = ZloArr[(size_t)b * NZ + k];
  float Zhi = ZhiArr[(size_t)b * NZ + 4096] - ZhiArr[(size_t)b * NZ + k];
  float4 rlo = {0,0,0,0}, rhi = {0,0,0,0};
  #pragma unroll
  for (int u = 0; u < 4; ++u) {
    int pos = 4*m + u;
    float msk = (pos < k) ? 1.f : 0.f;
    int rc = pos < N ? pos : N - 1;
    size_t o = ((size_t)b << 12) + rc;
    float wlo = e2lo[o] * msk, whi = e2hi[o] * msk;
    float4 v = ((const float4*)Vs)[o * 64 + lane];
    rlo.x += wlo*v.x; rlo.y += wlo*v.y; rlo.z += wlo*v.z; rlo.w += wlo*v.w;
    rhi.x += whi*v.x; rhi.y += whi*v.y; rhi.z += whi*v.z; rhi.w += whi*v.w;
  }
  float Z = a * Zhi + cc * Zlo;
  float rz = 1.f / Z;
  float bs = bias[0];
  float4 o4;
  o4.x = fmaxf((a*(pht.x - phb.x - rhi.x) + cc*(plo.x + rlo.x)) * rz + bs, 0.f);
  o4.y = fmaxf((a*(pht.y - phb.y - rhi.y) + cc*(plo.y + rlo.y)) * rz + bs, 0.f);
  o4.z = fmaxf((a*(pht.z - phb.z - rhi.z) + cc*(plo.z + rlo.z)) * rz + bs, 0.f);
  o4.w = fmaxf((a*(pht.w - phb.w - rhi.w) + cc*(plo.w + rlo.w)) * rz + bs, 0.f);
  ((float4*)out)[i * 64 + lane] = o4;
}

// ---------------- launch -------------------------------------------------------
extern "C" void kernel_launch(void* const* d_in, const int* in_sizes, int n_in,
                              void* d_out, int out_size, void* d_ws, size_t ws_size,
                              hipStream_t stream) {
  const float* seq  = (const float*)d_in[0];
  const float* Wf   = (const float*)d_in[1];
  const float* w1   = (const float*)d_in[2];
  const float* b1   = (const float*)d_in[3];
  const float* w2   = (const float*)d_in[4];
  const float* b2   = (const float*)d_in[5];
  const float* bias = (const float*)d_in[6];
  float* out = (float*)d_out;

  // ws layout: scalars | Vs | union(A2 | prefix arrays) | W3  (same need as R3)
  size_t need = (size_t)8 * BN * 4 + (size_t)BN * D * 4
              + (size_t)BN * 512 * 2 + (size_t)256 * 768 * 2;
  if (ws_size < need) return;

  float* f1   = (float*)d_ws;
  float* f2   = f1 + BN;
  float* sF2  = f2 + BN;
  float* e2lo = sF2 + BN;
  float* e2hi = e2lo + BN;
  int* sIdx   = (int*)(e2hi + BN);
  int* rank   = sIdx + BN;
  int* kArr   = rank + BN;
  float* Vs   = (float*)(kArr + BN);
  char* uni   = (char*)(Vs + (size_t)BN * D);
  ushort* A2  = (ushort*)uni;                 // dead after k_mfma
  float* PrefLo = (float*)uni;                // written after k_mfma
  float* PrefHi = PrefLo + (size_t)B * NP4 * D;
  float* SupLo  = PrefHi + (size_t)B * NP4 * D;
  float* SupHi  = SupLo + (size_t)B * NSUP * D;
  float* SupZlo = SupHi + (size_t)B * NSUP * D;
  float* SupZhi = SupZlo + B * NSUP;
  float* ZloArr = SupZhi + B * NSUP;
  float* ZhiArr = ZloArr + (size_t)B * NZ;
  ushort* W3  = (ushort*)(uni + (size_t)BN * 512 * 2);

  hipMemsetAsync(rank, 0, (size_t)BN * sizeof(int), stream);
  k_f1f2<<<dim3(BN/4), 256, 0, stream>>>(seq, w1, b1, w2, b2, f1, f2);
  k_wsplit<<<dim3(256), 256, 0, stream>>>(Wf, W3);
  k_rank_count<<<dim3(N/1024, N/256, B), 256, 0, stream>>>(f2, rank);
  k_scatter<<<dim3(BN/256), 256, 0, stream>>>(f2, rank, sF2, sIdx, e2lo, e2hi);
  k_findk<<<dim3(N/256, B), 256, 0, stream>>>(f1, sF2, kArr);
  k_split<<<dim3(BN/4), 256, 0, stream>>>(seq, sIdx, A2);
  k_mfma<<<dim3(BN/64), 256, 0, stream>>>(A2, W3, Vs);
  k_supstats<<<dim3(NSUP/4, B), 256, 0, stream>>>(Vs, e2lo, e2hi, SupLo, SupHi, SupZlo, SupZhi);
  k_supscan<<<dim3(B), 256, 0, stream>>>(SupLo, SupHi, SupZlo, SupZhi, PrefLo, PrefHi, ZloArr, ZhiArr);
  k_prefwrite<<<dim3(NSUP/4, B), 256, 0, stream>>>(Vs, e2lo, e2hi, SupLo, SupHi,
      SupZlo, SupZhi, PrefLo, PrefHi, ZloArr, ZhiArr);
  k_combine2<<<dim3(BN/4), 256, 0, stream>>>(f1, kArr, e2lo, e2hi, Vs,
      PrefLo, PrefHi, ZloArr, ZhiArr, bias, out);
}

// Round 5
// 130.683 us; speedup vs baseline: 2.1466x; 1.0404x over previous
//
#include <hip/hip_runtime.h>
#include <hip/hip_bf16.h>
#include <math.h>

#define B 8
#define N 4096
#define D 256
#define BN (B*N)
#define NSUP 64       // 64-row superchunks per batch
#define NP4 1025      // vector prefix rows per batch (every 4th pos + total)
#define NZ 4097       // scalar prefix entries per batch (every pos + total)

typedef __attribute__((ext_vector_type(8))) short bf16x8;
typedef __attribute__((ext_vector_type(4))) float f32x4;

#define GLD16(src, dst) __builtin_amdgcn_global_load_lds( \
    (const __attribute__((address_space(1))) void*)(src), \
    (__attribute__((address_space(3))) void*)(dst), 16, 0, 0)

// ---------------- K1: f1/f2 dot products + zero rank (one wave per row) --------
__global__ __launch_bounds__(256) void k_f1f2(const float* __restrict__ seq,
    const float* __restrict__ w1, const float* __restrict__ b1,
    const float* __restrict__ w2, const float* __restrict__ b2,
    float* __restrict__ f1, float* __restrict__ f2, int* __restrict__ rank) {
  int wave = threadIdx.x >> 6;
  int lane = threadIdx.x & 63;
  long row = (long)blockIdx.x * 4 + wave;
  float4 v = ((const float4*)(seq + row * D))[lane];
  float4 a = ((const float4*)w1)[lane];
  float4 b = ((const float4*)w2)[lane];
  float s1 = v.x*a.x + v.y*a.y + v.z*a.z + v.w*a.w;
  float s2 = v.x*b.x + v.y*b.y + v.z*b.z + v.w*b.w;
  for (int off = 32; off; off >>= 1) {
    s1 += __shfl_xor(s1, off, 64);
    s2 += __shfl_xor(s2, off, 64);
  }
  if (lane == 0) {
    f1[row] = s1 + b1[0];
    f2[row] = s2 + b2[0];
    rank[row] = 0;                      // replaces the 40us fillBuffer dispatch
  }
}

// ---------------- K2a: partial rank counts (tiled O(N^2), 64-bit keys) ---------
__global__ __launch_bounds__(256) void k_rank_count(const float* __restrict__ f2,
    int* __restrict__ rank) {
  __shared__ unsigned long long skey[256];
  int b = blockIdx.z;
  int tid = threadIdx.x;
  const float* fb = f2 + (long)b * N;
  int p = blockIdx.y * 256 + tid;
  unsigned int up = __float_as_uint(fb[p]);
  up ^= (unsigned int)(((int)up >> 31) | 0x80000000);
  skey[tid] = ((unsigned long long)up << 12) | (unsigned)p;
  unsigned long long kj[4];
  int jbase = blockIdx.x * 1024;
  #pragma unroll
  for (int q = 0; q < 4; ++q) {
    int j = jbase + q * 256 + tid;
    unsigned int uj = __float_as_uint(fb[j]);
    uj ^= (unsigned int)(((int)uj >> 31) | 0x80000000);
    kj[q] = ((unsigned long long)uj << 12) | (unsigned)j;
  }
  __syncthreads();
  int c[4] = {0, 0, 0, 0};
  const ulonglong2* sk2 = (const ulonglong2*)skey;
  #pragma unroll 4
  for (int pp = 0; pp < 128; ++pp) {
    ulonglong2 kk = sk2[pp];
    #pragma unroll
    for (int q = 0; q < 4; ++q) {
      c[q] += (kk.x < kj[q]) ? 1 : 0;
      c[q] += (kk.y < kj[q]) ? 1 : 0;
    }
  }
  #pragma unroll
  for (int q = 0; q < 4; ++q)
    atomicAdd(&rank[(long)b * N + jbase + q * 256 + tid], c[q]);
}

// ---------------- K2b: scatter into sorted order -------------------------------
__global__ __launch_bounds__(256) void k_scatter(const float* __restrict__ f2,
    const int* __restrict__ rank, float* __restrict__ sF2, int* __restrict__ sIdx,
    float* __restrict__ e2lo, float* __restrict__ e2hi) {
  long idx = (long)blockIdx.x * 256 + threadIdx.x;
  int b = (int)(idx >> 12);
  int j = (int)(idx & (N - 1));
  float v = f2[idx];
  int cnt = rank[idx];
  long o = (long)b * N + cnt;
  sF2[o] = v;
  sIdx[o] = j;
  e2lo[o] = expf(0.01f * v);
  e2hi[o] = expf(v);
}

// ---------------- K2c: split gathered seq rows into bf16 hi|lo -----------------
__global__ __launch_bounds__(256) void k_split(const float* __restrict__ seq,
    const int* __restrict__ sIdx, ushort* __restrict__ A2) {
  int wid = threadIdx.x >> 6, lane = threadIdx.x & 63;
  size_t p = (size_t)blockIdx.x * 4 + wid;
  int b = (int)(p >> 12);
  int j = sIdx[p];
  float4 v = ((const float4*)(seq + (((size_t)b << 12) + j) * D))[lane];
  float xs[4] = {v.x, v.y, v.z, v.w};
  ushort hu[4], lu[4];
  #pragma unroll
  for (int c = 0; c < 4; ++c) {
    __hip_bfloat16 hb = __float2bfloat16(xs[c]);
    float hf = __bfloat162float(hb);
    __hip_bfloat16 lb = __float2bfloat16(xs[c] - hf);
    hu[c] = *(ushort*)&hb; lu[c] = *(ushort*)&lb;
  }
  *(ushort4*)(A2 + (p << 9) + lane * 4) = make_ushort4(hu[0], hu[1], hu[2], hu[3]);
  *(ushort4*)(A2 + (p << 9) + 256 + lane * 4) = make_ushort4(lu[0], lu[1], lu[2], lu[3]);
}

// ---------------- K2d: W -> W3t[n][768] = [Wh | Wl | Wh] (transposed) ----------
__global__ __launch_bounds__(256) void k_wsplit(const float* __restrict__ W,
    ushort* __restrict__ W3) {
  int n = blockIdx.x;
  int k = threadIdx.x;
  float x = W[(size_t)k * D + n];
  __hip_bfloat16 h = __float2bfloat16(x);
  float hf = __bfloat162float(h);
  __hip_bfloat16 l = __float2bfloat16(x - hf);
  ushort hu = *(ushort*)&h, lu = *(ushort*)&l;
  W3[(size_t)n * 768 + k] = hu;
  W3[(size_t)n * 768 + 256 + k] = lu;
  W3[(size_t)n * 768 + 512 + k] = hu;
}

// ---------------- K3: Vs = A2(split) @ W3(split), bf16 MFMA, K=768 -------------
__global__ __launch_bounds__(256) void k_mfma(const ushort* __restrict__ A2,
    const ushort* __restrict__ W3, float* __restrict__ Vs) {
  __shared__ __align__(16) ushort As[64][64];
  __shared__ __align__(16) ushort Bs[256][64];
  int tid = threadIdx.x;
  int wid = tid >> 6, lane = tid & 63;
  int mBase = blockIdx.x * 64;
  int lr = lane >> 3;
  int lc = (lane & 7) * 8;
  int wr = wid >> 1, wc = wid & 1;
  int g = lane >> 4, r16 = lane & 15;

  f32x4 acc[2][8];
  #pragma unroll
  for (int m = 0; m < 2; ++m)
    #pragma unroll
    for (int n = 0; n < 8; ++n) {
      acc[m][n][0] = 0.f; acc[m][n][1] = 0.f; acc[m][n][2] = 0.f; acc[m][n][3] = 0.f;
    }

  for (int kt = 0; kt < 768; kt += 64) {
    int seg = kt >> 8;
    int aoff = ((seg == 2) ? 256 : 0) + (kt & 255);
    __syncthreads();
    #pragma unroll
    for (int q = 0; q < 2; ++q) {
      int r0 = q * 32 + wid * 8;
      GLD16(A2 + (((size_t)(mBase + r0 + lr)) << 9) + aoff + lc, &As[r0][0]);
    }
    #pragma unroll
    for (int q = 0; q < 8; ++q) {
      int r0 = q * 32 + wid * 8;
      GLD16(W3 + (size_t)(r0 + lr) * 768 + kt + lc, &Bs[r0][0]);
    }
    __syncthreads();
    #pragma unroll
    for (int kk = 0; kk < 64; kk += 32) {
      bf16x8 av[2], bv[8];
      #pragma unroll
      for (int m = 0; m < 2; ++m)
        av[m] = *(const bf16x8*)&As[wr*32 + m*16 + r16][kk + g*8];
      #pragma unroll
      for (int n = 0; n < 8; ++n)
        bv[n] = *(const bf16x8*)&Bs[wc*128 + n*16 + r16][kk + g*8];
      #pragma unroll
      for (int m = 0; m < 2; ++m)
        #pragma unroll
        for (int n = 0; n < 8; ++n)
          acc[m][n] = __builtin_amdgcn_mfma_f32_16x16x32_bf16(av[m], bv[n], acc[m][n], 0, 0, 0);
    }
  }
  #pragma unroll
  for (int m = 0; m < 2; ++m)
    #pragma unroll
    for (int n = 0; n < 8; ++n) {
      int col = wc*128 + n*16 + r16;
      #pragma unroll
      for (int j = 0; j < 4; ++j) {
        int row = mBase + wr*32 + m*16 + g*4 + j;
        Vs[(size_t)row * D + col] = acc[m][n][j];
      }
    }
}

// ---------------- K4a: per-super (64 rows) weighted sums, float4 ---------------
__global__ __launch_bounds__(256) void k_supstats(const float* __restrict__ Vs,
    const float* __restrict__ e2lo, const float* __restrict__ e2hi,
    float* __restrict__ SupLo, float* __restrict__ SupHi,
    float* __restrict__ SupZlo, float* __restrict__ SupZhi) {
  int wid = threadIdx.x >> 6, lane = threadIdx.x & 63;
  int s = blockIdx.x * 4 + wid;
  int b = blockIdx.y;
  size_t rbase = ((size_t)b << 12) + (size_t)s * 64;
  const float4* vsrc = (const float4*)Vs + rbase * 64 + lane;
  float4 alo = {0,0,0,0}, ahi = {0,0,0,0};
  float zlo = 0.f, zhi = 0.f;
  #pragma unroll 8
  for (int r = 0; r < 64; ++r) {
    float wlo = e2lo[rbase + r], whi = e2hi[rbase + r];
    float4 v = vsrc[(size_t)r * 64];
    alo.x += wlo*v.x; alo.y += wlo*v.y; alo.z += wlo*v.z; alo.w += wlo*v.w;
    ahi.x += whi*v.x; ahi.y += whi*v.y; ahi.z += whi*v.z; ahi.w += whi*v.w;
    zlo += wlo; zhi += whi;
  }
  ((float4*)SupLo)[((size_t)b * NSUP + s) * 64 + lane] = alo;
  ((float4*)SupHi)[((size_t)b * NSUP + s) * 64 + lane] = ahi;
  if (lane == 0) { SupZlo[b*NSUP+s] = zlo; SupZhi[b*NSUP+s] = zhi; }
}

// ---------------- K4b: exclusive scan over 64 supers + totals ------------------
__global__ __launch_bounds__(256) void k_supscan(float* __restrict__ SupLo,
    float* __restrict__ SupHi, float* __restrict__ SupZlo, float* __restrict__ SupZhi,
    float* __restrict__ PrefLo, float* __restrict__ PrefHi,
    float* __restrict__ ZloArr, float* __restrict__ ZhiArr) {
  int b = blockIdx.x, t = threadIdx.x;
  if (t < 64) {
    float4* lo = (float4*)SupLo + (size_t)b * NSUP * 64 + t;
    float4* hi = (float4*)SupHi + (size_t)b * NSUP * 64 + t;
    float4 rl = {0,0,0,0}, rh = {0,0,0,0};
    for (int s = 0; s < NSUP; s += 8) {
      float4 tl[8], th[8];
      #pragma unroll
      for (int u = 0; u < 8; ++u) { tl[u] = lo[(size_t)(s+u)*64]; th[u] = hi[(size_t)(s+u)*64]; }
      #pragma unroll
      for (int u = 0; u < 8; ++u) {
        lo[(size_t)(s+u)*64] = rl; hi[(size_t)(s+u)*64] = rh;
        rl.x+=tl[u].x; rl.y+=tl[u].y; rl.z+=tl[u].z; rl.w+=tl[u].w;
        rh.x+=th[u].x; rh.y+=th[u].y; rh.z+=th[u].z; rh.w+=th[u].w;
      }
    }
    ((float4*)PrefLo)[((size_t)b * NP4 + 1024) * 64 + t] = rl;
    ((float4*)PrefHi)[((size_t)b * NP4 + 1024) * 64 + t] = rh;
  } else if (t == 64) {
    float r = 0.f;
    for (int s = 0; s < NSUP; ++s) { float x = SupZlo[b*NSUP+s]; SupZlo[b*NSUP+s] = r; r += x; }
    ZloArr[(size_t)b * NZ + 4096] = r;
  } else if (t == 65) {
    float r = 0.f;
    for (int s = 0; s < NSUP; ++s) { float x = SupZhi[b*NSUP+s]; SupZhi[b*NSUP+s] = r; r += x; }
    ZhiArr[(size_t)b * NZ + 4096] = r;
  }
}

// ---------------- K4c: write gran-4 vector prefix + gran-1 scalar prefix -------
__global__ __launch_bounds__(256) void k_prefwrite(const float* __restrict__ Vs,
    const float* __restrict__ e2lo, const float* __restrict__ e2hi,
    const float* __restrict__ SupLo, const float* __restrict__ SupHi,
    const float* __restrict__ SupZlo, const float* __restrict__ SupZhi,
    float* __restrict__ PrefLo, float* __restrict__ PrefHi,
    float* __restrict__ ZloArr, float* __restrict__ ZhiArr) {
  int wid = threadIdx.x >> 6, lane = threadIdx.x & 63;
  int s = blockIdx.x * 4 + wid;
  int b = blockIdx.y;
  size_t rbase = ((size_t)b << 12) + (size_t)s * 64;
  const float4* vsrc = (const float4*)Vs + rbase * 64 + lane;
  float4 rl = ((const float4*)SupLo)[((size_t)b * NSUP + s) * 64 + lane];
  float4 rh = ((const float4*)SupHi)[((size_t)b * NSUP + s) * 64 + lane];
  float zlo = SupZlo[b*NSUP+s], zhi = SupZhi[b*NSUP+s];
  float4* plo = (float4*)PrefLo + ((size_t)b * NP4 + s * 16) * 64 + lane;
  float4* phi = (float4*)PrefHi + ((size_t)b * NP4 + s * 16) * 64 + lane;
  float* zl = ZloArr + (size_t)b * NZ + s * 64;
  float* zh = ZhiArr + (size_t)b * NZ + s * 64;
  #pragma unroll 4
  for (int r = 0; r < 64; ++r) {
    float wlo = e2lo[rbase + r], whi = e2hi[rbase + r];
    float4 v = vsrc[(size_t)r * 64];
    if ((r & 3) == 0) { plo[(size_t)(r>>2) * 64] = rl; phi[(size_t)(r>>2) * 64] = rh; }
    if (lane == 0) { zl[r] = zlo; zh[r] = zhi; }
    rl.x += wlo*v.x; rl.y += wlo*v.y; rl.z += wlo*v.z; rl.w += wlo*v.w;
    rh.x += whi*v.x; rh.y += whi*v.y; rh.z += whi*v.z; rh.w += whi*v.w;
    zlo += wlo; zhi += whi;
  }
}

// ---------------- K5a: threshold rank per row (LDS binary search) --------------
__global__ __launch_bounds__(256) void k_findk(const float* __restrict__ f1,
    const float* __restrict__ sF2, int* __restrict__ kArr) {
  __shared__ float sf[N];
  int b = blockIdx.y;
  for (int t = threadIdx.x; t < N; t += 256) sf[t] = sF2[((size_t)b << 12) + t];
  __syncthreads();
  int i = blockIdx.x * 256 + threadIdx.x;
  float t = -f1[((size_t)b << 12) + i];
  int lo = 0, hi = N;
  while (lo < hi) { int mid = (lo + hi) >> 1; if (sf[mid] <= t) lo = mid + 1; else hi = mid; }
  kArr[((size_t)b << 12) + i] = lo;
}

// ---------------- K5b: combine (1 wave/row, float4, <=3-row residual) ----------
__global__ __launch_bounds__(256) void k_combine2(const float* __restrict__ f1,
    const int* __restrict__ kArr, const float* __restrict__ e2lo,
    const float* __restrict__ e2hi, const float* __restrict__ Vs,
    const float* __restrict__ PrefLo, const float* __restrict__ PrefHi,
    const float* __restrict__ ZloArr, const float* __restrict__ ZhiArr,
    const float* __restrict__ bias, float* __restrict__ out) {
  int wid = threadIdx.x >> 6, lane = threadIdx.x & 63;
  size_t i = (size_t)blockIdx.x * 4 + wid;
  int b = (int)(i >> 12);
  float f1v = f1[i];
  int k = kArr[i];
  float a = expf(f1v), cc = expf(0.01f * f1v);
  int m = k >> 2;
  float4 plo = ((const float4*)PrefLo)[((size_t)b * NP4 + m) * 64 + lane];
  float4 phb = ((const float4*)PrefHi)[((size_t)b * NP4 + m) * 64 + lane];
  float4 pht = ((const float4*)PrefHi)[((size_t)b * NP4 + 1024) * 64 + lane];
  float Zlo = ZloArr[(size_t)b * NZ + k];
  float Zhi = ZhiArr[(size_t)b * NZ + 4096] - ZhiArr[(size_t)b * NZ + k];
  float4 rlo = {0,0,0,0}, rhi = {0,0,0,0};
  #pragma unroll
  for (int u = 0; u < 4; ++u) {
    int pos = 4*m + u;
    float msk = (pos < k) ? 1.f : 0.f;
    int rc = pos < N ? pos : N - 1;
    size_t o = ((size_t)b << 12) + rc;
    float wlo = e2lo[o] * msk, whi = e2hi[o] * msk;
    float4 v = ((const float4*)Vs)[o * 64 + lane];
    rlo.x += wlo*v.x; rlo.y += wlo*v.y; rlo.z += wlo*v.z; rlo.w += wlo*v.w;
    rhi.x += whi*v.x; rhi.y += whi*v.y; rhi.z += whi*v.z; rhi.w += whi*v.w;
  }
  float Z = a * Zhi + cc * Zlo;
  float rz = 1.f / Z;
  float bs = bias[0];
  float4 o4;
  o4.x = fmaxf((a*(pht.x - phb.x - rhi.x) + cc*(plo.x + rlo.x)) * rz + bs, 0.f);
  o4.y = fmaxf((a*(pht.y - phb.y - rhi.y) + cc*(plo.y + rlo.y)) * rz + bs, 0.f);
  o4.z = fmaxf((a*(pht.z - phb.z - rhi.z) + cc*(plo.z + rlo.z)) * rz + bs, 0.f);
  o4.w = fmaxf((a*(pht.w - phb.w - rhi.w) + cc*(plo.w + rlo.w)) * rz + bs, 0.f);
  ((float4*)out)[i * 64 + lane] = o4;
}

// ---------------- launch -------------------------------------------------------
extern "C" void kernel_launch(void* const* d_in, const int* in_sizes, int n_in,
                              void* d_out, int out_size, void* d_ws, size_t ws_size,
                              hipStream_t stream) {
  const float* seq  = (const float*)d_in[0];
  const float* Wf   = (const float*)d_in[1];
  const float* w1   = (const float*)d_in[2];
  const float* b1   = (const float*)d_in[3];
  const float* w2   = (const float*)d_in[4];
  const float* b2   = (const float*)d_in[5];
  const float* bias = (const float*)d_in[6];
  float* out = (float*)d_out;

  size_t need = (size_t)8 * BN * 4 + (size_t)BN * D * 4
              + (size_t)BN * 512 * 2 + (size_t)256 * 768 * 2;
  if (ws_size < need) return;

  float* f1   = (float*)d_ws;
  float* f2   = f1 + BN;
  float* sF2  = f2 + BN;
  float* e2lo = sF2 + BN;
  float* e2hi = e2lo + BN;
  int* sIdx   = (int*)(e2hi + BN);
  int* rank   = sIdx + BN;
  int* kArr   = rank + BN;
  float* Vs   = (float*)(kArr + BN);
  char* uni   = (char*)(Vs + (size_t)BN * D);
  ushort* A2  = (ushort*)uni;                 // dead after k_mfma
  float* PrefLo = (float*)uni;                // written after k_mfma
  float* PrefHi = PrefLo + (size_t)B * NP4 * D;
  float* SupLo  = PrefHi + (size_t)B * NP4 * D;
  float* SupHi  = SupLo + (size_t)B * NSUP * D;
  float* SupZlo = SupHi + (size_t)B * NSUP * D;
  float* SupZhi = SupZlo + B * NSUP;
  float* ZloArr = SupZhi + B * NSUP;
  float* ZhiArr = ZloArr + (size_t)B * NZ;
  ushort* W3  = (ushort*)(uni + (size_t)BN * 512 * 2);

  k_f1f2<<<dim3(BN/4), 256, 0, stream>>>(seq, w1, b1, w2, b2, f1, f2, rank);
  k_wsplit<<<dim3(256), 256, 0, stream>>>(Wf, W3);
  k_rank_count<<<dim3(N/1024, N/256, B), 256, 0, stream>>>(f2, rank);
  k_scatter<<<dim3(BN/256), 256, 0, stream>>>(f2, rank, sF2, sIdx, e2lo, e2hi);
  k_findk<<<dim3(N/256, B), 256, 0, stream>>>(f1, sF2, kArr);
  k_split<<<dim3(BN/4), 256, 0, stream>>>(seq, sIdx, A2);
  k_mfma<<<dim3(BN/64), 256, 0, stream>>>(A2, W3, Vs);
  k_supstats<<<dim3(NSUP/4, B), 256, 0, stream>>>(Vs, e2lo, e2hi, SupLo, SupHi, SupZlo, SupZhi);
  k_supscan<<<dim3(B), 256, 0, stream>>>(SupLo, SupHi, SupZlo, SupZhi, PrefLo, PrefHi, ZloArr, ZhiArr);
  k_prefwrite<<<dim3(NSUP/4, B), 256, 0, stream>>>(Vs, e2lo, e2hi, SupLo, SupHi,
      SupZlo, SupZhi, PrefLo, PrefHi, ZloArr, ZhiArr);
  k_combine2<<<dim3(BN/4), 256, 0, stream>>>(f1, kArr, e2lo, e2hi, Vs,
      PrefLo, PrefHi, ZloArr, ZhiArr, bias, out);
}

// Round 6
// 111.169 us; speedup vs baseline: 2.5234x; 1.1755x over previous
//
#include <hip/hip_runtime.h>
#include <hip/hip_bf16.h>
#include <math.h>

#define B 8
#define N 4096
#define D 256
#define BN (B*N)
#define NSUP 64       // 64-row superchunks per batch
#define NS1 65        // super bases + grand total
#define NR 1025       // relative gran-4 prefix rows per batch (+ zero row 1024)
#define NZ 4097       // gran-1 relative scalar prefix (+ zero entry 4096)

typedef __attribute__((ext_vector_type(8))) short bf16x8;
typedef __attribute__((ext_vector_type(4))) float f32x4;

#define GLD16(src, dst) __builtin_amdgcn_global_load_lds( \
    (const __attribute__((address_space(1))) void*)(src), \
    (__attribute__((address_space(3))) void*)(dst), 16, 0, 0)

__device__ __forceinline__ ushort bf16_hi(float x) {
  __hip_bfloat16 h = __float2bfloat16(x);
  return *(ushort*)&h;
}
__device__ __forceinline__ ushort bf16_lo(float x) {
  __hip_bfloat16 h = __float2bfloat16(x);
  float hf = __bfloat162float(h);
  __hip_bfloat16 l = __float2bfloat16(x - hf);
  return *(ushort*)&l;
}

// ---------------- K1: f1/f2 dot products + zero rank (one wave per row) --------
__global__ __launch_bounds__(256) void k_f1f2(const float* __restrict__ seq,
    const float* __restrict__ w1, const float* __restrict__ b1,
    const float* __restrict__ w2, const float* __restrict__ b2,
    float* __restrict__ f1, float* __restrict__ f2, int* __restrict__ rank) {
  int wave = threadIdx.x >> 6;
  int lane = threadIdx.x & 63;
  long row = (long)blockIdx.x * 4 + wave;
  float4 v = ((const float4*)(seq + row * D))[lane];
  float4 a = ((const float4*)w1)[lane];
  float4 b = ((const float4*)w2)[lane];
  float s1 = v.x*a.x + v.y*a.y + v.z*a.z + v.w*a.w;
  float s2 = v.x*b.x + v.y*b.y + v.z*b.z + v.w*b.w;
  for (int off = 32; off; off >>= 1) {
    s1 += __shfl_xor(s1, off, 64);
    s2 += __shfl_xor(s2, off, 64);
  }
  if (lane == 0) {
    f1[row] = s1 + b1[0];
    f2[row] = s2 + b2[0];
    rank[row] = 0;
  }
}

// ---------------- K2a: partial rank counts (tiled O(N^2), 64-bit keys) ---------
__global__ __launch_bounds__(256) void k_rank_count(const float* __restrict__ f2,
    int* __restrict__ rank) {
  __shared__ unsigned long long skey[256];
  int b = blockIdx.z;
  int tid = threadIdx.x;
  const float* fb = f2 + (long)b * N;
  int p = blockIdx.y * 256 + tid;
  unsigned int up = __float_as_uint(fb[p]);
  up ^= (unsigned int)(((int)up >> 31) | 0x80000000);
  skey[tid] = ((unsigned long long)up << 12) | (unsigned)p;
  unsigned long long kj[4];
  int jbase = blockIdx.x * 1024;
  #pragma unroll
  for (int q = 0; q < 4; ++q) {
    int j = jbase + q * 256 + tid;
    unsigned int uj = __float_as_uint(fb[j]);
    uj ^= (unsigned int)(((int)uj >> 31) | 0x80000000);
    kj[q] = ((unsigned long long)uj << 12) | (unsigned)j;
  }
  __syncthreads();
  int c[4] = {0, 0, 0, 0};
  const ulonglong2* sk2 = (const ulonglong2*)skey;
  #pragma unroll 4
  for (int pp = 0; pp < 128; ++pp) {
    ulonglong2 kk = sk2[pp];
    #pragma unroll
    for (int q = 0; q < 4; ++q) {
      c[q] += (kk.x < kj[q]) ? 1 : 0;
      c[q] += (kk.y < kj[q]) ? 1 : 0;
    }
  }
  #pragma unroll
  for (int q = 0; q < 4; ++q)
    atomicAdd(&rank[(long)b * N + jbase + q * 256 + tid], c[q]);
}

// ---------------- K2b: scatter into sorted order -------------------------------
__global__ __launch_bounds__(256) void k_scatter(const float* __restrict__ f2,
    const int* __restrict__ rank, float* __restrict__ sF2, int* __restrict__ sIdx,
    float* __restrict__ e2lo, float* __restrict__ e2hi) {
  long idx = (long)blockIdx.x * 256 + threadIdx.x;
  int b = (int)(idx >> 12);
  int j = (int)(idx & (N - 1));
  float v = f2[idx];
  int cnt = rank[idx];
  long o = (long)b * N + cnt;
  sF2[o] = v;
  sIdx[o] = j;
  e2lo[o] = expf(0.01f * v);
  e2hi[o] = expf(v);
}

// ---------------- K2d: W -> W3t[n][768] = [Wh | Wl | Wh] (transposed) ----------
__global__ __launch_bounds__(256) void k_wsplit(const float* __restrict__ W,
    ushort* __restrict__ W3) {
  int n = blockIdx.x;
  int k = threadIdx.x;
  float x = W[(size_t)k * D + n];
  ushort hu = bf16_hi(x), lu = bf16_lo(x);
  W3[(size_t)n * 768 + k] = hu;
  W3[(size_t)n * 768 + 256 + k] = lu;
  W3[(size_t)n * 768 + 512 + k] = hu;
}

// ---------------- K3: Vs = gather(seq)@W, split-bf16 MFMA, K=768 ---------------
// A segments: [Ah | Ah | Al] vs W3 = [Wh | Wl | Wh] -> Ah*Wh + Ah*Wl + Al*Wh.
// A gather+split fused (reg-staged into padded As); Bs XOR-swizzled (T2, rule 21).
__global__ __launch_bounds__(256) void k_mfma(const float* __restrict__ seq,
    const int* __restrict__ sIdx, const ushort* __restrict__ W3,
    float* __restrict__ Vs) {
  __shared__ __align__(16) ushort As[64][72];   // padded: conflict-free rw
  __shared__ __align__(16) ushort Bs[256][64];  // XOR-swizzled within rows
  int tid = threadIdx.x;
  int wid = tid >> 6, lane = tid & 63;
  int mBase = blockIdx.x * 64;
  int b = mBase >> 12;
  // A staging: thread t -> row ar, quarter aq (16 floats)
  int ar = tid >> 2, aq = tid & 3;
  const float* aSrc = seq + (((size_t)(b << 12)) + sIdx[mBase + ar]) * D + aq * 16;
  // B staging via GLD16 with pre-swizzled global column-block
  int lr = lane >> 3;
  int lcSw = (((lane & 7) ^ (lr & 7))) * 8;
  // fragment geometry
  int wr = wid >> 1, wc = wid & 1, g = lane >> 4, r16 = lane & 15;
  int bswz = r16 & 7;

  f32x4 acc[2][8];
  #pragma unroll
  for (int m = 0; m < 2; ++m)
    #pragma unroll
    for (int n = 0; n < 8; ++n) {
      acc[m][n][0] = 0.f; acc[m][n][1] = 0.f; acc[m][n][2] = 0.f; acc[m][n][3] = 0.f;
    }

  for (int kt = 0; kt < 768; kt += 64) {
    int acol = kt & 255;
    // issue A global loads early (overlap previous compute tail)
    float4 xv[4];
    #pragma unroll
    for (int i = 0; i < 4; ++i) xv[i] = *(const float4*)(aSrc + acol + i * 4);
    ushort ou[16];
    if (kt < 512) {
      #pragma unroll
      for (int i = 0; i < 4; ++i) {
        ou[i*4+0] = bf16_hi(xv[i].x); ou[i*4+1] = bf16_hi(xv[i].y);
        ou[i*4+2] = bf16_hi(xv[i].z); ou[i*4+3] = bf16_hi(xv[i].w);
      }
    } else {
      #pragma unroll
      for (int i = 0; i < 4; ++i) {
        ou[i*4+0] = bf16_lo(xv[i].x); ou[i*4+1] = bf16_lo(xv[i].y);
        ou[i*4+2] = bf16_lo(xv[i].z); ou[i*4+3] = bf16_lo(xv[i].w);
      }
    }
    __syncthreads();                       // previous tile fully consumed
    #pragma unroll
    for (int i = 0; i < 4; ++i)
      *(ushort4*)&As[ar][aq * 16 + i * 4] =
          make_ushort4(ou[i*4+0], ou[i*4+1], ou[i*4+2], ou[i*4+3]);
    #pragma unroll
    for (int q = 0; q < 8; ++q) {
      int r0 = q * 32 + wid * 8;
      GLD16(W3 + (size_t)(r0 + lr) * 768 + kt + lcSw, &Bs[r0][0]);
    }
    __syncthreads();                       // barrier drains vm+lgkm
    #pragma unroll
    for (int kk = 0; kk < 64; kk += 32) {
      bf16x8 av[2], bv[8];
      #pragma unroll
      for (int m = 0; m < 2; ++m)
        av[m] = *(const bf16x8*)&As[wr*32 + m*16 + r16][kk + g*8];
      int jb = (kk >> 3) + g;
      int jj = jb ^ bswz;
      #pragma unroll
      for (int n = 0; n < 8; ++n) {
        int row = wc*128 + n*16 + r16;
        bv[n] = *(const bf16x8*)((const char*)Bs + row * 128 + jj * 16);
      }
      #pragma unroll
      for (int m = 0; m < 2; ++m)
        #pragma unroll
        for (int n = 0; n < 8; ++n)
          acc[m][n] = __builtin_amdgcn_mfma_f32_16x16x32_bf16(av[m], bv[n], acc[m][n], 0, 0, 0);
    }
  }
  #pragma unroll
  for (int m = 0; m < 2; ++m)
    #pragma unroll
    for (int n = 0; n < 8; ++n) {
      int col = wc*128 + n*16 + r16;
      #pragma unroll
      for (int j = 0; j < 4; ++j) {
        int row = mBase + wr*32 + m*16 + g*4 + j;
        Vs[(size_t)row * D + col] = acc[m][n][j];
      }
    }
}

// ---------------- K4a: one Vs pass: relative gran-4/gran-1 prefixes + totals ---
__global__ __launch_bounds__(256) void k_statspref(const float* __restrict__ Vs,
    const float* __restrict__ e2lo, const float* __restrict__ e2hi,
    float* __restrict__ RelLo, float* __restrict__ RelHi,
    float* __restrict__ ZrelLo, float* __restrict__ ZrelHi,
    float* __restrict__ SupBaseLo, float* __restrict__ SupBaseHi,
    float* __restrict__ SupZlo, float* __restrict__ SupZhi) {
  int wid = threadIdx.x >> 6, lane = threadIdx.x & 63;
  int s = blockIdx.x * 4 + wid;
  int b = blockIdx.y;
  size_t rbase = ((size_t)b << 12) + (size_t)s * 64;
  const float4* vsrc = (const float4*)Vs + rbase * 64 + lane;
  float4* relLo = (float4*)RelLo + ((size_t)b * NR + s * 16) * 64 + lane;
  float4* relHi = (float4*)RelHi + ((size_t)b * NR + s * 16) * 64 + lane;
  float* zlp = ZrelLo + (size_t)b * NZ + s * 64;
  float* zhp = ZrelHi + (size_t)b * NZ + s * 64;
  float4 rl = {0,0,0,0}, rh = {0,0,0,0};
  float zl = 0.f, zh = 0.f;
  #pragma unroll 4
  for (int r = 0; r < 64; ++r) {
    float wlo = e2lo[rbase + r], whi = e2hi[rbase + r];
    float4 v = vsrc[(size_t)r * 64];
    if ((r & 3) == 0) { relLo[(size_t)(r>>2) * 64] = rl; relHi[(size_t)(r>>2) * 64] = rh; }
    if (lane == 0) { zlp[r] = zl; zhp[r] = zh; }
    rl.x += wlo*v.x; rl.y += wlo*v.y; rl.z += wlo*v.z; rl.w += wlo*v.w;
    rh.x += whi*v.x; rh.y += whi*v.y; rh.z += whi*v.z; rh.w += whi*v.w;
    zl += wlo; zh += whi;
  }
  ((float4*)SupBaseLo)[((size_t)b * NS1 + s) * 64 + lane] = rl;
  ((float4*)SupBaseHi)[((size_t)b * NS1 + s) * 64 + lane] = rh;
  if (lane == 0) { SupZlo[b*NS1+s] = zl; SupZhi[b*NS1+s] = zh; }
}

// ---------------- K4b: scan 64 super bases (exclusive) + zero rows -------------
__global__ __launch_bounds__(256) void k_supscan(float* __restrict__ SupBaseLo,
    float* __restrict__ SupBaseHi, float* __restrict__ SupZlo,
    float* __restrict__ SupZhi, float* __restrict__ RelLo, float* __restrict__ RelHi,
    float* __restrict__ ZrelLo, float* __restrict__ ZrelHi) {
  int b = blockIdx.x, t = threadIdx.x;
  if (t < 64) {
    float4* lo = (float4*)SupBaseLo + (size_t)b * NS1 * 64 + t;
    float4* hi = (float4*)SupBaseHi + (size_t)b * NS1 * 64 + t;
    float4 rl = {0,0,0,0}, rh = {0,0,0,0};
    for (int s = 0; s < NSUP; s += 8) {
      float4 tl[8], th[8];
      #pragma unroll
      for (int u = 0; u < 8; ++u) { tl[u] = lo[(size_t)(s+u)*64]; th[u] = hi[(size_t)(s+u)*64]; }
      #pragma unroll
      for (int u = 0; u < 8; ++u) {
        lo[(size_t)(s+u)*64] = rl; hi[(size_t)(s+u)*64] = rh;
        rl.x+=tl[u].x; rl.y+=tl[u].y; rl.z+=tl[u].z; rl.w+=tl[u].w;
        rh.x+=th[u].x; rh.y+=th[u].y; rh.z+=th[u].z; rh.w+=th[u].w;
      }
    }
    lo[(size_t)NSUP*64] = rl;     // grand total row
    hi[(size_t)NSUP*64] = rh;
  } else if (t < 128) {
    float4 z = {0,0,0,0};
    ((float4*)RelLo)[((size_t)b * NR + 1024) * 64 + (t - 64)] = z;
  } else if (t < 192) {
    float4 z = {0,0,0,0};
    ((float4*)RelHi)[((size_t)b * NR + 1024) * 64 + (t - 128)] = z;
  } else if (t == 192) {
    float r = 0.f;
    for (int s = 0; s < NSUP; ++s) { float x = SupZlo[b*NS1+s]; SupZlo[b*NS1+s] = r; r += x; }
    SupZlo[b*NS1+NSUP] = r;
    ZrelLo[(size_t)b * NZ + 4096] = 0.f;
  } else if (t == 193) {
    float r = 0.f;
    for (int s = 0; s < NSUP; ++s) { float x = SupZhi[b*NS1+s]; SupZhi[b*NS1+s] = r; r += x; }
    SupZhi[b*NS1+NSUP] = r;
    ZrelHi[(size_t)b * NZ + 4096] = 0.f;
  }
}

// ---------------- K5a: threshold rank per row (LDS binary search) --------------
__global__ __launch_bounds__(256) void k_findk(const float* __restrict__ f1,
    const float* __restrict__ sF2, int* __restrict__ kArr) {
  __shared__ float sf[N];
  int b = blockIdx.y;
  for (int t = threadIdx.x; t < N; t += 256) sf[t] = sF2[((size_t)b << 12) + t];
  __syncthreads();
  int i = blockIdx.x * 256 + threadIdx.x;
  float t = -f1[((size_t)b << 12) + i];
  int lo = 0, hi = N;
  while (lo < hi) { int mid = (lo + hi) >> 1; if (sf[mid] <= t) lo = mid + 1; else hi = mid; }
  kArr[((size_t)b << 12) + i] = lo;
}

// ---------------- K5b: combine (1 wave/row, float4, <=3-row residual) ----------
__global__ __launch_bounds__(256) void k_combine2(const float* __restrict__ f1,
    const int* __restrict__ kArr, const float* __restrict__ e2lo,
    const float* __restrict__ e2hi, const float* __restrict__ Vs,
    const float* __restrict__ RelLo, const float* __restrict__ RelHi,
    const float* __restrict__ SupBaseLo, const float* __restrict__ SupBaseHi,
    const float* __restrict__ SupZlo, const float* __restrict__ SupZhi,
    const float* __restrict__ ZrelLo, const float* __restrict__ ZrelHi,
    const float* __restrict__ bias, float* __restrict__ out) {
  int wid = threadIdx.x >> 6, lane = threadIdx.x & 63;
  size_t i = (size_t)blockIdx.x * 4 + wid;
  int b = (int)(i >> 12);
  float f1v = f1[i];
  int k = kArr[i];
  float a = expf(f1v), cc = expf(0.01f * f1v);
  int m = k >> 2;
  int s = k >> 6;
  float4 sblo = ((const float4*)SupBaseLo)[((size_t)b * NS1 + s) * 64 + lane];
  float4 sbhi = ((const float4*)SupBaseHi)[((size_t)b * NS1 + s) * 64 + lane];
  float4 pht  = ((const float4*)SupBaseHi)[((size_t)b * NS1 + NSUP) * 64 + lane];
  float4 rlp  = ((const float4*)RelLo)[((size_t)b * NR + m) * 64 + lane];
  float4 rhp  = ((const float4*)RelHi)[((size_t)b * NR + m) * 64 + lane];
  float4 plo = {sblo.x+rlp.x, sblo.y+rlp.y, sblo.z+rlp.z, sblo.w+rlp.w};
  float4 phb = {sbhi.x+rhp.x, sbhi.y+rhp.y, sbhi.z+rhp.z, sbhi.w+rhp.w};
  float Zlo = SupZlo[b*NS1+s] + ZrelLo[(size_t)b * NZ + k];
  float Zhi = SupZhi[b*NS1+NSUP] - (SupZhi[b*NS1+s] + ZrelHi[(size_t)b * NZ + k]);
  float4 rlo = {0,0,0,0}, rhi = {0,0,0,0};
  #pragma unroll
  for (int u = 0; u < 4; ++u) {
    int pos = 4*m + u;
    float msk = (pos < k) ? 1.f : 0.f;
    int rc = pos < N ? pos : N - 1;
    size_t o = ((size_t)b << 12) + rc;
    float wlo = e2lo[o] * msk, whi = e2hi[o] * msk;
    float4 v = ((const float4*)Vs)[o * 64 + lane];
    rlo.x += wlo*v.x; rlo.y += wlo*v.y; rlo.z += wlo*v.z; rlo.w += wlo*v.w;
    rhi.x += whi*v.x; rhi.y += whi*v.y; rhi.z += whi*v.z; rhi.w += whi*v.w;
  }
  float Z = a * Zhi + cc * Zlo;
  float rz = 1.f / Z;
  float bs = bias[0];
  float4 o4;
  o4.x = fmaxf((a*(pht.x - phb.x - rhi.x) + cc*(plo.x + rlo.x)) * rz + bs, 0.f);
  o4.y = fmaxf((a*(pht.y - phb.y - rhi.y) + cc*(plo.y + rlo.y)) * rz + bs, 0.f);
  o4.z = fmaxf((a*(pht.z - phb.z - rhi.z) + cc*(plo.z + rlo.z)) * rz + bs, 0.f);
  o4.w = fmaxf((a*(pht.w - phb.w - rhi.w) + cc*(plo.w + rlo.w)) * rz + bs, 0.f);
  ((float4*)out)[i * 64 + lane] = o4;
}

// ---------------- launch -------------------------------------------------------
extern "C" void kernel_launch(void* const* d_in, const int* in_sizes, int n_in,
                              void* d_out, int out_size, void* d_ws, size_t ws_size,
                              hipStream_t stream) {
  const float* seq  = (const float*)d_in[0];
  const float* Wf   = (const float*)d_in[1];
  const float* w1   = (const float*)d_in[2];
  const float* b1   = (const float*)d_in[3];
  const float* w2   = (const float*)d_in[4];
  const float* b2   = (const float*)d_in[5];
  const float* bias = (const float*)d_in[6];
  float* out = (float*)d_out;

  size_t need = (size_t)4 * (8*BN + (size_t)BN*D + 2*(size_t)B*NR*D + 2*(size_t)B*NS1*D
              + 2*B*NS1 + 2*(size_t)B*NZ) + (size_t)256*768*2;
  if (ws_size < need) return;

  float* f1   = (float*)d_ws;
  float* f2   = f1 + BN;
  float* sF2  = f2 + BN;
  float* e2lo = sF2 + BN;
  float* e2hi = e2lo + BN;
  int* sIdx   = (int*)(e2hi + BN);
  int* rank   = sIdx + BN;
  int* kArr   = rank + BN;
  float* Vs   = (float*)(kArr + BN);
  float* RelLo = Vs + (size_t)BN * D;
  float* RelHi = RelLo + (size_t)B * NR * D;
  float* SupBaseLo = RelHi + (size_t)B * NR * D;
  float* SupBaseHi = SupBaseLo + (size_t)B * NS1 * D;
  float* SupZlo = SupBaseHi + (size_t)B * NS1 * D;
  float* SupZhi = SupZlo + B * NS1;
  float* ZrelLo = SupZhi + B * NS1;
  float* ZrelHi = ZrelLo + (size_t)B * NZ;
  ushort* W3 = (ushort*)(ZrelHi + (size_t)B * NZ);

  k_f1f2<<<dim3(BN/4), 256, 0, stream>>>(seq, w1, b1, w2, b2, f1, f2, rank);
  k_wsplit<<<dim3(256), 256, 0, stream>>>(Wf, W3);
  k_rank_count<<<dim3(N/1024, N/256, B), 256, 0, stream>>>(f2, rank);
  k_scatter<<<dim3(BN/256), 256, 0, stream>>>(f2, rank, sF2, sIdx, e2lo, e2hi);
  k_findk<<<dim3(N/256, B), 256, 0, stream>>>(f1, sF2, kArr);
  k_mfma<<<dim3(BN/64), 256, 0, stream>>>(seq, sIdx, W3, Vs);
  k_statspref<<<dim3(NSUP/4, B), 256, 0, stream>>>(Vs, e2lo, e2hi,
      RelLo, RelHi, ZrelLo, ZrelHi, SupBaseLo, SupBaseHi, SupZlo, SupZhi);
  k_supscan<<<dim3(B), 256, 0, stream>>>(SupBaseLo, SupBaseHi, SupZlo, SupZhi,
      RelLo, RelHi, ZrelLo, ZrelHi);
  k_combine2<<<dim3(BN/4), 256, 0, stream>>>(f1, kArr, e2lo, e2hi, Vs,
      RelLo, RelHi, SupBaseLo, SupBaseHi, SupZlo, SupZhi, ZrelLo, ZrelHi, bias, out);
}

// Round 7
// 91.531 us; speedup vs baseline: 3.0648x; 1.2146x over previous
//
#include <hip/hip_runtime.h>
#include <hip/hip_bf16.h>
#include <math.h>

#define B 8
#define N 4096
#define D 256
#define BN (B*N)
#define NSUP 64       // 64-row supers per batch (1 super == 1 mfma block tile)
#define NS1 65        // super bases + grand total
#define NR1 4097      // gran-1 prefix rows per batch (+ zero row 4096)

typedef __attribute__((ext_vector_type(8))) short bf16x8;
typedef __attribute__((ext_vector_type(4))) float f32x4;

#define GLD16(src, dst) __builtin_amdgcn_global_load_lds( \
    (const __attribute__((address_space(1))) void*)(src), \
    (__attribute__((address_space(3))) void*)(dst), 16, 0, 0)

__device__ __forceinline__ ushort bf16_hi(float x) {
  __hip_bfloat16 h = __float2bfloat16(x);
  return *(ushort*)&h;
}
__device__ __forceinline__ ushort bf16_lo(float x) {
  __hip_bfloat16 h = __float2bfloat16(x);
  float hf = __bfloat162float(h);
  __hip_bfloat16 l = __float2bfloat16(x - hf);
  return *(ushort*)&l;
}

// ---------------- K1: f1/f2 dots + zero rank + W split (fused) -----------------
__global__ __launch_bounds__(256) void k_f1f2w(const float* __restrict__ seq,
    const float* __restrict__ w1, const float* __restrict__ b1,
    const float* __restrict__ w2, const float* __restrict__ b2,
    const float* __restrict__ W, float* __restrict__ f1, float* __restrict__ f2,
    int* __restrict__ rank, ushort* __restrict__ W3) {
  if (blockIdx.x >= BN/4) {                       // W -> W3t[n][768]=[Wh|Wl|Wh]
    int n = blockIdx.x - BN/4;
    int k = threadIdx.x;
    float x = W[(size_t)k * D + n];
    ushort hu = bf16_hi(x), lu = bf16_lo(x);
    W3[(size_t)n * 768 + k] = hu;
    W3[(size_t)n * 768 + 256 + k] = lu;
    W3[(size_t)n * 768 + 512 + k] = hu;
    return;
  }
  int wave = threadIdx.x >> 6;
  int lane = threadIdx.x & 63;
  long row = (long)blockIdx.x * 4 + wave;
  float4 v = ((const float4*)(seq + row * D))[lane];
  float4 a = ((const float4*)w1)[lane];
  float4 b = ((const float4*)w2)[lane];
  float s1 = v.x*a.x + v.y*a.y + v.z*a.z + v.w*a.w;
  float s2 = v.x*b.x + v.y*b.y + v.z*b.z + v.w*b.w;
  for (int off = 32; off; off >>= 1) {
    s1 += __shfl_xor(s1, off, 64);
    s2 += __shfl_xor(s2, off, 64);
  }
  if (lane == 0) {
    f1[row] = s1 + b1[0];
    f2[row] = s2 + b2[0];
    rank[row] = 0;
  }
}

// ---------------- K2a: partial rank counts (tiled O(N^2), 64-bit keys) ---------
__global__ __launch_bounds__(256) void k_rank_count(const float* __restrict__ f2,
    int* __restrict__ rank) {
  __shared__ unsigned long long skey[256];
  int b = blockIdx.z;
  int tid = threadIdx.x;
  const float* fb = f2 + (long)b * N;
  int p = blockIdx.y * 256 + tid;
  unsigned int up = __float_as_uint(fb[p]);
  up ^= (unsigned int)(((int)up >> 31) | 0x80000000);
  skey[tid] = ((unsigned long long)up << 12) | (unsigned)p;
  unsigned long long kj[4];
  int jbase = blockIdx.x * 1024;
  #pragma unroll
  for (int q = 0; q < 4; ++q) {
    int j = jbase + q * 256 + tid;
    unsigned int uj = __float_as_uint(fb[j]);
    uj ^= (unsigned int)(((int)uj >> 31) | 0x80000000);
    kj[q] = ((unsigned long long)uj << 12) | (unsigned)j;
  }
  __syncthreads();
  int c[4] = {0, 0, 0, 0};
  const ulonglong2* sk2 = (const ulonglong2*)skey;
  #pragma unroll 4
  for (int pp = 0; pp < 128; ++pp) {
    ulonglong2 kk = sk2[pp];
    #pragma unroll
    for (int q = 0; q < 4; ++q) {
      c[q] += (kk.x < kj[q]) ? 1 : 0;
      c[q] += (kk.y < kj[q]) ? 1 : 0;
    }
  }
  #pragma unroll
  for (int q = 0; q < 4; ++q)
    atomicAdd(&rank[(long)b * N + jbase + q * 256 + tid], c[q]);
}

// ---------------- K2b: scatter into sorted order -------------------------------
__global__ __launch_bounds__(256) void k_scatter(const float* __restrict__ f2,
    const int* __restrict__ rank, float* __restrict__ sF2, int* __restrict__ sIdx,
    float* __restrict__ e2lo, float* __restrict__ e2hi) {
  long idx = (long)blockIdx.x * 256 + threadIdx.x;
  int b = (int)(idx >> 12);
  int j = (int)(idx & (N - 1));
  float v = f2[idx];
  int cnt = rank[idx];
  long o = (long)b * N + cnt;
  sF2[o] = v;
  sIdx[o] = j;
  e2lo[o] = expf(0.01f * v);
  e2hi[o] = expf(v);
}

// ---------------- K3: split-bf16 MFMA GEMM + fused prefix epilogue -------------
// A segs [Ah|Ah|Al] x W3=[Wh|Wl|Wh]. Block = one 64-row super; epilogue does the
// within-super exclusive prefix (gran-1) via a 64KB LDS transpose tile.
__global__ __launch_bounds__(256) void k_mfma(const float* __restrict__ seq,
    const int* __restrict__ sIdx, const ushort* __restrict__ W3,
    const float* __restrict__ e2lo, const float* __restrict__ e2hi,
    float* __restrict__ RelLo, float* __restrict__ RelHi,
    float* __restrict__ ZrelLo, float* __restrict__ ZrelHi,
    float* __restrict__ SupBaseLo, float* __restrict__ SupBaseHi,
    float* __restrict__ SupZlo, float* __restrict__ SupZhi) {
  __shared__ __align__(16) char smem[64 * 256 * 4];   // 64KB union
  ushort (*As)[72] = (ushort(*)[72])smem;
  ushort (*Bs)[64] = (ushort(*)[64])(smem + 64 * 72 * 2);
  int tid = threadIdx.x;
  int wid = tid >> 6, lane = tid & 63;
  int mBase = blockIdx.x * 64;
  int b = mBase >> 12;
  int ar = tid >> 2, aq = tid & 3;
  const float* aSrc = seq + (((size_t)(b << 12)) + sIdx[mBase + ar]) * D + aq * 16;
  int lr = lane >> 3;
  int lcSw = (((lane & 7) ^ (lr & 7))) * 8;
  int wr = wid >> 1, wc = wid & 1, g = lane >> 4, r16 = lane & 15;
  int bswz = r16 & 7;

  f32x4 acc[2][8];
  #pragma unroll
  for (int m = 0; m < 2; ++m)
    #pragma unroll
    for (int n = 0; n < 8; ++n) {
      acc[m][n][0] = 0.f; acc[m][n][1] = 0.f; acc[m][n][2] = 0.f; acc[m][n][3] = 0.f;
    }

  for (int kt = 0; kt < 768; kt += 64) {
    int acol = kt & 255;
    float4 xv[4];
    #pragma unroll
    for (int i = 0; i < 4; ++i) xv[i] = *(const float4*)(aSrc + acol + i * 4);
    ushort ou[16];
    if (kt < 512) {
      #pragma unroll
      for (int i = 0; i < 4; ++i) {
        ou[i*4+0] = bf16_hi(xv[i].x); ou[i*4+1] = bf16_hi(xv[i].y);
        ou[i*4+2] = bf16_hi(xv[i].z); ou[i*4+3] = bf16_hi(xv[i].w);
      }
    } else {
      #pragma unroll
      for (int i = 0; i < 4; ++i) {
        ou[i*4+0] = bf16_lo(xv[i].x); ou[i*4+1] = bf16_lo(xv[i].y);
        ou[i*4+2] = bf16_lo(xv[i].z); ou[i*4+3] = bf16_lo(xv[i].w);
      }
    }
    __syncthreads();
    #pragma unroll
    for (int i = 0; i < 4; ++i)
      *(ushort4*)&As[ar][aq * 16 + i * 4] =
          make_ushort4(ou[i*4+0], ou[i*4+1], ou[i*4+2], ou[i*4+3]);
    #pragma unroll
    for (int q = 0; q < 8; ++q) {
      int r0 = q * 32 + wid * 8;
      GLD16(W3 + (size_t)(r0 + lr) * 768 + kt + lcSw, &Bs[r0][0]);
    }
    __syncthreads();
    #pragma unroll
    for (int kk = 0; kk < 64; kk += 32) {
      bf16x8 av[2], bv[8];
      #pragma unroll
      for (int m = 0; m < 2; ++m)
        av[m] = *(const bf16x8*)&As[wr*32 + m*16 + r16][kk + g*8];
      int jb = (kk >> 3) + g;
      int jj = jb ^ bswz;
      #pragma unroll
      for (int n = 0; n < 8; ++n) {
        int row = wc*128 + n*16 + r16;
        bv[n] = *(const bf16x8*)((const char*)Bs + row * 128 + jj * 16);
      }
      #pragma unroll
      for (int m = 0; m < 2; ++m)
        #pragma unroll
        for (int n = 0; n < 8; ++n)
          acc[m][n] = __builtin_amdgcn_mfma_f32_16x16x32_bf16(av[m], bv[n], acc[m][n], 0, 0, 0);
    }
  }

  // ---- epilogue: LDS transpose + within-super exclusive prefix (gran-1) ----
  __syncthreads();                         // As/Bs fully consumed
  float (*Vt)[256] = (float(*)[256])smem;  // XOR-swizzled by (row>>2)&3
  int cswz = (g & 3) << 2;
  #pragma unroll
  for (int m = 0; m < 2; ++m)
    #pragma unroll
    for (int n = 0; n < 8; ++n) {
      int col = (wc*128 + n*16 + r16) ^ cswz;
      #pragma unroll
      for (int j = 0; j < 4; ++j)
        Vt[wr*32 + m*16 + g*4 + j][col] = acc[m][n][j];
    }
  __syncthreads();
  int d = tid;
  int s = (mBase >> 6) & 63;
  size_t rb = (size_t)mBase;               // flat sorted base (= b*4096 + s*64)
  float rl = 0.f, rh = 0.f;
  float* pLo = RelLo + ((size_t)b * NR1 + (size_t)s * 64) * D + d;
  float* pHi = RelHi + ((size_t)b * NR1 + (size_t)s * 64) * D + d;
  #pragma unroll 8
  for (int r = 0; r < 64; ++r) {
    float wlo = e2lo[rb + r], whi = e2hi[rb + r];
    float v = Vt[r][d ^ (((r >> 2) & 3) << 2)];
    pLo[(size_t)r * D] = rl;
    pHi[(size_t)r * D] = rh;
    rl += wlo * v; rh += whi * v;
  }
  SupBaseLo[((size_t)b * NS1 + s) * D + d] = rl;
  SupBaseHi[((size_t)b * NS1 + s) * D + d] = rh;
  if (tid == 0) {
    float z = 0.f;
    #pragma unroll 8
    for (int r = 0; r < 64; ++r) { ZrelLo[(size_t)b * NR1 + s*64 + r] = z; z += e2lo[rb + r]; }
    SupZlo[b*NS1+s] = z;
  } else if (tid == 64) {
    float z = 0.f;
    #pragma unroll 8
    for (int r = 0; r < 64; ++r) { ZrelHi[(size_t)b * NR1 + s*64 + r] = z; z += e2hi[rb + r]; }
    SupZhi[b*NS1+s] = z;
  }
}

// ---------------- K4: scan 64 super bases (exclusive) + zero rows --------------
__global__ __launch_bounds__(256) void k_supscan(float* __restrict__ SupBaseLo,
    float* __restrict__ SupBaseHi, float* __restrict__ SupZlo,
    float* __restrict__ SupZhi, float* __restrict__ RelLo, float* __restrict__ RelHi,
    float* __restrict__ ZrelLo, float* __restrict__ ZrelHi) {
  int b = blockIdx.x, t = threadIdx.x;
  if (t < 64) {
    float4* lo = (float4*)SupBaseLo + (size_t)b * NS1 * 64 + t;
    float4* hi = (float4*)SupBaseHi + (size_t)b * NS1 * 64 + t;
    float4 rl = {0,0,0,0}, rh = {0,0,0,0};
    for (int s = 0; s < NSUP; s += 8) {
      float4 tl[8], th[8];
      #pragma unroll
      for (int u = 0; u < 8; ++u) { tl[u] = lo[(size_t)(s+u)*64]; th[u] = hi[(size_t)(s+u)*64]; }
      #pragma unroll
      for (int u = 0; u < 8; ++u) {
        lo[(size_t)(s+u)*64] = rl; hi[(size_t)(s+u)*64] = rh;
        rl.x+=tl[u].x; rl.y+=tl[u].y; rl.z+=tl[u].z; rl.w+=tl[u].w;
        rh.x+=th[u].x; rh.y+=th[u].y; rh.z+=th[u].z; rh.w+=th[u].w;
      }
    }
    lo[(size_t)NSUP*64] = rl;     // grand totals
    hi[(size_t)NSUP*64] = rh;
  } else if (t < 128) {
    float4 z = {0,0,0,0};
    ((float4*)RelLo)[((size_t)b * NR1 + 4096) * 64 + (t - 64)] = z;
  } else if (t < 192) {
    float4 z = {0,0,0,0};
    ((float4*)RelHi)[((size_t)b * NR1 + 4096) * 64 + (t - 128)] = z;
  } else if (t == 192) {
    float r = 0.f;
    for (int s = 0; s < NSUP; ++s) { float x = SupZlo[b*NS1+s]; SupZlo[b*NS1+s] = r; r += x; }
    SupZlo[b*NS1+NSUP] = r;
    ZrelLo[(size_t)b * NR1 + 4096] = 0.f;
  } else if (t == 193) {
    float r = 0.f;
    for (int s = 0; s < NSUP; ++s) { float x = SupZhi[b*NS1+s]; SupZhi[b*NS1+s] = r; r += x; }
    SupZhi[b*NS1+NSUP] = r;
    ZrelHi[(size_t)b * NR1 + 4096] = 0.f;
  }
}

// ---------------- K5: combine (binary search + gran-1 prefix, no residual) -----
__global__ __launch_bounds__(256) void k_combine2(const float* __restrict__ f1,
    const float* __restrict__ sF2,
    const float* __restrict__ RelLo, const float* __restrict__ RelHi,
    const float* __restrict__ SupBaseLo, const float* __restrict__ SupBaseHi,
    const float* __restrict__ SupZlo, const float* __restrict__ SupZhi,
    const float* __restrict__ ZrelLo, const float* __restrict__ ZrelHi,
    const float* __restrict__ bias, float* __restrict__ out) {
  int wid = threadIdx.x >> 6, lane = threadIdx.x & 63;
  size_t i = (size_t)blockIdx.x * 4 + wid;
  int b = (int)(i >> 12);
  float f1v = f1[i];
  const float* sb = sF2 + ((size_t)b << 12);
  float t = -f1v;
  int lo = 0, hi = N;
  while (lo < hi) { int mid = (lo + hi) >> 1; if (sb[mid] <= t) lo = mid + 1; else hi = mid; }
  int k = lo;
  int s = k >> 6;
  float a = expf(f1v), cc = expf(0.01f * f1v);
  float4 rl4  = ((const float4*)RelLo)[((size_t)b * NR1 + k) * 64 + lane];
  float4 rh4  = ((const float4*)RelHi)[((size_t)b * NR1 + k) * 64 + lane];
  float4 sblo = ((const float4*)SupBaseLo)[((size_t)b * NS1 + s) * 64 + lane];
  float4 sbhi = ((const float4*)SupBaseHi)[((size_t)b * NS1 + s) * 64 + lane];
  float4 pht  = ((const float4*)SupBaseHi)[((size_t)b * NS1 + NSUP) * 64 + lane];
  float Zlo = SupZlo[b*NS1+s] + ZrelLo[(size_t)b * NR1 + k];
  float Zhi = SupZhi[b*NS1+NSUP] - SupZhi[b*NS1+s] - ZrelHi[(size_t)b * NR1 + k];
  float Z = a * Zhi + cc * Zlo;
  float rz = 1.f / Z;
  float bs = bias[0];
  float4 o4;
  o4.x = fmaxf((a*(pht.x - sbhi.x - rh4.x) + cc*(sblo.x + rl4.x)) * rz + bs, 0.f);
  o4.y = fmaxf((a*(pht.y - sbhi.y - rh4.y) + cc*(sblo.y + rl4.y)) * rz + bs, 0.f);
  o4.z = fmaxf((a*(pht.z - sbhi.z - rh4.z) + cc*(sblo.z + rl4.z)) * rz + bs, 0.f);
  o4.w = fmaxf((a*(pht.w - sbhi.w - rh4.w) + cc*(sblo.w + rl4.w)) * rz + bs, 0.f);
  ((float4*)out)[i * 64 + lane] = o4;
}

// ---------------- launch -------------------------------------------------------
extern "C" void kernel_launch(void* const* d_in, const int* in_sizes, int n_in,
                              void* d_out, int out_size, void* d_ws, size_t ws_size,
                              hipStream_t stream) {
  const float* seq  = (const float*)d_in[0];
  const float* Wf   = (const float*)d_in[1];
  const float* w1   = (const float*)d_in[2];
  const float* b1   = (const float*)d_in[3];
  const float* w2   = (const float*)d_in[4];
  const float* b2   = (const float*)d_in[5];
  const float* bias = (const float*)d_in[6];
  float* out = (float*)d_out;

  size_t need = (size_t)4 * (7*BN + 2*(size_t)B*NR1*D + 2*(size_t)B*NS1*D
              + 2*B*NS1 + 2*(size_t)B*NR1) + (size_t)256*768*2;
  if (ws_size < need) return;

  float* f1   = (float*)d_ws;
  float* f2   = f1 + BN;
  float* sF2  = f2 + BN;
  float* e2lo = sF2 + BN;
  float* e2hi = e2lo + BN;
  int* sIdx   = (int*)(e2hi + BN);
  int* rank   = sIdx + BN;
  float* RelLo = (float*)(rank + BN);
  float* RelHi = RelLo + (size_t)B * NR1 * D;
  float* SupBaseLo = RelHi + (size_t)B * NR1 * D;
  float* SupBaseHi = SupBaseLo + (size_t)B * NS1 * D;
  float* SupZlo = SupBaseHi + (size_t)B * NS1 * D;
  float* SupZhi = SupZlo + B * NS1;
  float* ZrelLo = SupZhi + B * NS1;
  float* ZrelHi = ZrelLo + (size_t)B * NR1;
  ushort* W3 = (ushort*)(ZrelHi + (size_t)B * NR1);

  k_f1f2w<<<dim3(BN/4 + 256), 256, 0, stream>>>(seq, w1, b1, w2, b2, Wf,
      f1, f2, rank, W3);
  k_rank_count<<<dim3(N/1024, N/256, B), 256, 0, stream>>>(f2, rank);
  k_scatter<<<dim3(BN/256), 256, 0, stream>>>(f2, rank, sF2, sIdx, e2lo, e2hi);
  k_mfma<<<dim3(BN/64), 256, 0, stream>>>(seq, sIdx, W3, e2lo, e2hi,
      RelLo, RelHi, ZrelLo, ZrelHi, SupBaseLo, SupBaseHi, SupZlo, SupZhi);
  k_supscan<<<dim3(B), 256, 0, stream>>>(SupBaseLo, SupBaseHi, SupZlo, SupZhi,
      RelLo, RelHi, ZrelLo, ZrelHi);
  k_combine2<<<dim3(BN/4), 256, 0, stream>>>(f1, sF2,
      RelLo, RelHi, SupBaseLo, SupBaseHi, SupZlo, SupZhi, ZrelLo, ZrelHi, bias, out);
}